// Round 10
// baseline (581.544 us; speedup 1.0000x reference)
//
#include <hip/hip_runtime.h>
#include <cmath>

typedef short bf16x8 __attribute__((ext_vector_type(8)));
typedef float f32x2 __attribute__((ext_vector_type(2)));
typedef float f32x4 __attribute__((ext_vector_type(4)));
typedef float f32x16 __attribute__((ext_vector_type(16)));

#define NSEQ 4096
#define BATCH 2
#define DIM 512
#define HEADS 8
#define NROWS (BATCH * NSEQ)   // 8192
#define QKVN (3 * DIM)         // 1536

__device__ __forceinline__ unsigned short f2bf(float f) {
  unsigned int u = __float_as_uint(f);
  u += 0x7fffu + ((u >> 16) & 1u);
  return (unsigned short)(u >> 16);
}
__device__ __forceinline__ float bf2f(unsigned short h) {
  return __uint_as_float(((unsigned int)h) << 16);
}
__device__ __forceinline__ void gload16(const unsigned short* g, unsigned short* l) {
  __builtin_amdgcn_global_load_lds((const __attribute__((address_space(1))) unsigned int*)g,
                                   (__attribute__((address_space(3))) unsigned int*)l, 16, 0, 0);
}

// ---------------- cos/sin tables ----------------
__global__ __launch_bounds__(256) void k_tables(const float* __restrict__ rot,
                                                float* __restrict__ cosT,
                                                float* __restrict__ sinT) {
  int i = blockIdx.x * 256 + threadIdx.x;
  float f = rot[i];
  cosT[i] = cosf(f);
  sinT[i] = sinf(f);
}

// ---------------- fp32 -> bf16 weight convert ----------------
__global__ __launch_bounds__(256) void k_cvt(const float* __restrict__ src,
                                             unsigned short* __restrict__ dst, int n) {
  int i = blockIdx.x * 256 + threadIdx.x;
  if (i < n) dst[i] = f2bf(src[i]);
}

// ---------------- LayerNorm: one wave per row ----------------
__global__ __launch_bounds__(256) void k_ln(const float* __restrict__ x,
                                            const float* __restrict__ w,
                                            const float* __restrict__ bb,
                                            unsigned short* __restrict__ xn) {
  int row = blockIdx.x * 4 + (threadIdx.x >> 6);
  int lane = threadIdx.x & 63;
  const float* xr = x + (size_t)row * DIM;
  float v[8];
  float s = 0.f;
#pragma unroll
  for (int j = 0; j < 8; ++j) { v[j] = xr[lane + j * 64]; s += v[j]; }
#pragma unroll
  for (int m = 1; m < 64; m <<= 1) s += __shfl_xor(s, m);
  float mu = s * (1.0f / DIM);
  float q = 0.f;
#pragma unroll
  for (int j = 0; j < 8; ++j) { float d = v[j] - mu; q += d * d; }
#pragma unroll
  for (int m = 1; m < 64; m <<= 1) q += __shfl_xor(q, m);
  float rs = rsqrtf(q * (1.0f / DIM) + 1e-5f);
#pragma unroll
  for (int j = 0; j < 8; ++j) {
    int col = lane + j * 64;
    xn[(size_t)row * DIM + col] = f2bf((v[j] - mu) * rs * w[col] + bb[col]);
  }
}

// ---------------- GEMM: C[M][N] = A[M][K] * B[N][K]^T (dbuf, 1 barrier/step) ----------------
template <int EPI>
__global__ __launch_bounds__(256) void k_gemm(const unsigned short* __restrict__ A,
                                              const unsigned short* __restrict__ B,
                                              void* __restrict__ C,
                                              const float* __restrict__ bias,
                                              int M, int N, int K) {
  __shared__ __align__(16) unsigned short As[2][128 * 32];
  __shared__ __align__(16) unsigned short Bs[2][128 * 32];
  int bm = blockIdx.x, bn = blockIdx.y;
  int tid = threadIdx.x;
  int lane = tid & 63, w = tid >> 6;
  int wm = (w >> 1) << 6, wn = (w & 1) << 6;
  f32x4 acc[4][4] = {};

#define GSTAGE(KT, BUF) do { \
  _Pragma("unroll") \
  for (int i = 0; i < 2; ++i) { \
    int c = tid + (i << 8); \
    int row = c >> 2, kc = (c & 3) << 3; \
    gload16(A + (size_t)(bm * 128 + row) * K + (KT) + kc, &As[BUF][(w * 64 + i * 256) * 8]); \
    gload16(B + (size_t)(bn * 128 + row) * K + (KT) + kc, &Bs[BUF][(w * 64 + i * 256) * 8]); \
  } } while (0)

  GSTAGE(0, 0);
  __syncthreads();
  int nk = K >> 5;
  for (int t = 0; t < nk; ++t) {
    int cur = t & 1;
    if (t + 1 < nk) GSTAGE((t + 1) << 5, cur ^ 1);
    bf16x8 af[4], bfr[4];
#pragma unroll
    for (int mi = 0; mi < 4; ++mi)
      af[mi] = *(const bf16x8*)&As[cur][(wm + mi * 16 + (lane & 15)) * 32 + ((lane >> 4) << 3)];
#pragma unroll
    for (int ni = 0; ni < 4; ++ni)
      bfr[ni] = *(const bf16x8*)&Bs[cur][(wn + ni * 16 + (lane & 15)) * 32 + ((lane >> 4) << 3)];
#pragma unroll
    for (int mi = 0; mi < 4; ++mi)
#pragma unroll
      for (int ni = 0; ni < 4; ++ni)
        acc[mi][ni] = __builtin_amdgcn_mfma_f32_16x16x32_bf16(af[mi], bfr[ni], acc[mi][ni], 0, 0, 0);
    __syncthreads();
  }
#undef GSTAGE
#pragma unroll
  for (int mi = 0; mi < 4; ++mi) {
#pragma unroll
    for (int ni = 0; ni < 4; ++ni) {
#pragma unroll
      for (int r = 0; r < 4; ++r) {
        int gm = bm * 128 + wm + mi * 16 + ((lane >> 4) << 2) + r;
        int gn = bn * 128 + wn + ni * 16 + (lane & 15);
        if (EPI == 0) {
          ((unsigned short*)C)[(size_t)gm * N + gn] = f2bf(acc[mi][ni][r]);
        } else {
          ((float*)C)[(size_t)gm * N + gn] = acc[mi][ni][r] + bias[gn];
        }
      }
    }
  }
}

// ------ RoPE + head split (+ V transpose); Q pre-scaled by 0.125*log2(e) (exp2-domain) ------
__global__ __launch_bounds__(256) void k_rope_split(const unsigned short* __restrict__ qkv,
                                                    const float* __restrict__ cosT,
                                                    const float* __restrict__ sinT,
                                                    unsigned short* __restrict__ qh,
                                                    unsigned short* __restrict__ kh,
                                                    unsigned short* __restrict__ vt) {
  __shared__ unsigned short vs[128][65];
  const float QSC = 0.125f * 1.44269504f;
  int nt = blockIdx.x, bh = blockIdx.y;
  int b = bh >> 3, h = bh & 7;
  int n0 = nt * 128;
  int t = threadIdx.x;
  int sub = t >> 3, cc = t & 7;
#pragma unroll
  for (int rr = 0; rr < 4; ++rr) {
    int row = rr * 32 + sub;
    int n = n0 + row;
    size_t base = ((size_t)(b * NSEQ + n)) * QKVN + h * 64 + cc * 8;
    const float* cb = cosT + ((size_t)(b * NSEQ + n)) * 64 + cc * 8;
    const float* sb = sinT + ((size_t)(b * NSEQ + n)) * 64 + cc * 8;
    float c[8], sn[8];
#pragma unroll
    for (int j = 0; j < 8; ++j) { c[j] = cb[j]; sn[j] = sb[j]; }
    bf16x8 qv = *(const bf16x8*)(qkv + base);
    bf16x8 kv = *(const bf16x8*)(qkv + base + 512);
    bf16x8 vv = *(const bf16x8*)(qkv + base + 1024);
    union { bf16x8 v; unsigned short u[8]; } yq, yk;
#pragma unroll
    for (int j = 0; j < 8; j += 2) {
      {
        float e = bf2f((unsigned short)qv[j]), o = bf2f((unsigned short)qv[j + 1]);
        yq.u[j]     = f2bf((e * c[j] - o * sn[j]) * QSC);
        yq.u[j + 1] = f2bf((o * c[j + 1] + e * sn[j + 1]) * QSC);
      }
      {
        float e = bf2f((unsigned short)kv[j]), o = bf2f((unsigned short)kv[j + 1]);
        yk.u[j]     = f2bf(e * c[j] - o * sn[j]);
        yk.u[j + 1] = f2bf(o * c[j + 1] + e * sn[j + 1]);
      }
      {
        float e = bf2f((unsigned short)vv[j]), o = bf2f((unsigned short)vv[j + 1]);
        vs[row][cc * 8 + j]     = f2bf(e * c[j] - o * sn[j]);
        vs[row][cc * 8 + j + 1] = f2bf(o * c[j + 1] + e * sn[j + 1]);
      }
    }
    *(bf16x8*)(qh + ((size_t)bh * NSEQ + n) * 64 + cc * 8) = yq.v;
    *(bf16x8*)(kh + ((size_t)bh * NSEQ + n) * 64 + cc * 8) = yk.v;
  }
  __syncthreads();
  int d = t >> 2, c4 = t & 3;
#pragma unroll
  for (int g = 0; g < 4; ++g) {
    union { bf16x8 v; unsigned short u[8]; } tv;
#pragma unroll
    for (int j = 0; j < 8; ++j) tv.u[j] = vs[c4 * 32 + g * 8 + j][d];
    *(bf16x8*)(vt + ((size_t)bh * 64 + d) * NSEQ + n0 + c4 * 32 + g * 8) = tv.v;
  }
}

// ---------------- Flash attention v10: KV-split-4, 64q/wave, bf16 partials ----
// 1024 blocks x 4 waves; block = (bh, 256-q tile, KV quarter of 1024 keys).
// Wave owns 64 q rows (frags A,B); every K/V ds_read_b128 feeds 2 MFMAs.
// P half-exchange: round-7-proven shfl_xor(32) + cndmask select.
// Partials: opart bf16 [quarter][bh][q][64], lpart f32 [quarter][bh][q].
__global__ __launch_bounds__(256, 4) void k_attn(const unsigned short* __restrict__ Qh,
                                                 const unsigned short* __restrict__ Kh,
                                                 const unsigned short* __restrict__ VT,
                                                 unsigned short* __restrict__ opart,
                                                 float* __restrict__ lpart) {
  __shared__ __align__(16) unsigned short Ks[2][64 * 64];
  __shared__ __align__(16) unsigned short Vs[2][64 * 64];
  int bid = blockIdx.x;
  int bh   = (bid & 7) + 8 * ((bid >> 7) & 1);  // XCD-pinned: bh%8 == bid%8
  int qt   = (bid >> 3) & 15;
  int quarter = (bid >> 8) & 3;
  int tid = threadIdx.x;
  int w = tid >> 6, lane = tid & 63;
  int lq = lane & 31, hi = lane >> 5;
  int q0 = qt * 256 + w * 64;
  int kv0 = quarter << 10;

  const unsigned short* Kbh = Kh + (size_t)bh * NSEQ * 64;
  const unsigned short* Vbh = VT + (size_t)bh * 64 * NSEQ;

  const unsigned short* QbA = Qh + ((size_t)bh * NSEQ + q0 + lq) * 64 + hi * 8;
  const unsigned short* QbB = QbA + 32 * 64;
  bf16x8 qfA[4], qfB[4];
#pragma unroll
  for (int j = 0; j < 4; ++j) {
    qfA[j] = *(const bf16x8*)(QbA + j * 16);
    qfB[j] = *(const bf16x8*)(QbB + j * 16);
  }

  // staging chunk geometry: chunk c -> row r=c>>3, source 16B slot (c&7)^(r&7)
  int c0 = w * 64 + lane;
  int r0 = c0 >> 3, sw0 = ((c0 & 7) ^ (r0 & 7)) << 3;
  int c1 = c0 + 256;
  int r1 = c1 >> 3, sw1 = ((c1 & 7) ^ (r1 & 7)) << 3;
  int ld0 = (w * 64) * 8, ld1 = (256 + w * 64) * 8;

  f32x16 accA0 = (f32x16)0.0f, accA1 = (f32x16)0.0f;
  f32x16 accB0 = (f32x16)0.0f, accB1 = (f32x16)0.0f;
  float lA = 0.f, lB = 0.f;
  int swz = (lq & 7) << 4;

  // prologue: stage tile 0 into buf 0
  gload16(Kbh + ((size_t)kv0 + r0) * 64 + sw0, &Ks[0][ld0]);
  gload16(Kbh + ((size_t)kv0 + r1) * 64 + sw1, &Ks[0][ld1]);
  gload16(Vbh + (size_t)r0 * NSEQ + kv0 + sw0, &Vs[0][ld0]);
  gload16(Vbh + (size_t)r1 * NSEQ + kv0 + sw1, &Vs[0][ld1]);
  __syncthreads();

  for (int t = 0; t < 16; ++t) {
    int cur = t & 1;
    if (t < 15) {
      int tg = kv0 + (t + 1) * 64;
      gload16(Kbh + ((size_t)tg + r0) * 64 + sw0, &Ks[cur ^ 1][ld0]);
      gload16(Kbh + ((size_t)tg + r1) * 64 + sw1, &Ks[cur ^ 1][ld1]);
      gload16(Vbh + (size_t)r0 * NSEQ + tg + sw0, &Vs[cur ^ 1][ld0]);
      gload16(Vbh + (size_t)r1 * NSEQ + tg + sw1, &Vs[cur ^ 1][ld1]);
    }
    const char* kb_ = (const char*)&Ks[cur][0];
    const char* vb_ = (const char*)&Vs[cur][0];
#pragma unroll
    for (int ph = 0; ph < 2; ++ph) {
      // ---- QK^T: 32 k-rows x 64 q (each a-read feeds both q-frags) ----
      f32x16 sA = (f32x16)0.0f, sB = (f32x16)0.0f;
      __builtin_amdgcn_s_setprio(1);
#pragma unroll
      for (int j = 0; j < 4; ++j) {
        int cb = j * 32 + hi * 16;
        bf16x8 a = *(const bf16x8*)(kb_ + (ph * 32 + lq) * 128 + (cb ^ swz));
        sA = __builtin_amdgcn_mfma_f32_32x32x16_bf16(a, qfA[j], sA, 0, 0, 0);
        sB = __builtin_amdgcn_mfma_f32_32x32x16_bf16(a, qfB[j], sB, 0, 0, 0);
      }
      __builtin_amdgcn_s_setprio(0);
      // ---- exp2 (raw) + packed sums ----
#pragma unroll
      for (int r = 0; r < 16; ++r) sA[r] = __builtin_amdgcn_exp2f(sA[r]);
#pragma unroll
      for (int r = 0; r < 16; ++r) sB[r] = __builtin_amdgcn_exp2f(sB[r]);
      {
        union { f32x16 v; f32x2 p[8]; } ua, ub; ua.v = sA; ub.v = sB;
        f32x2 a01 = ua.p[0] + ua.p[1], a23 = ua.p[2] + ua.p[3];
        f32x2 a45 = ua.p[4] + ua.p[5], a67 = ua.p[6] + ua.p[7];
        f32x2 ta = (a01 + a23) + (a45 + a67);
        lA += ta.x + ta.y;
        f32x2 b01 = ub.p[0] + ub.p[1], b23 = ub.p[2] + ub.p[3];
        f32x2 b45 = ub.p[4] + ub.p[5], b67 = ub.p[6] + ub.p[7];
        f32x2 tb = (b01 + b23) + (b45 + b67);
        lB += tb.x + tb.y;
      }
      // ---- pack P -> bf16 ----
      unsigned int dwA[8], dwB[8];
#pragma unroll
      for (int m = 0; m < 8; ++m) {
        asm("v_cvt_pk_bf16_f32 %0, %1, %2" : "=v"(dwA[m]) : "v"(sA[2 * m]), "v"(sA[2 * m + 1]));
        asm("v_cvt_pk_bf16_f32 %0, %1, %2" : "=v"(dwB[m]) : "v"(sB[2 * m]), "v"(sB[2 * m + 1]));
      }
      // ---- PV: each v-read feeds both q-frags; exchange via shfl_xor (proven) ----
      __builtin_amdgcn_s_setprio(1);
#pragma unroll
      for (int kk = 0; kk < 2; ++kk) {
        const int B = 4 * kk;
        unsigned int svA0 = hi ? dwA[B + 0] : dwA[B + 2];
        unsigned int svA1 = hi ? dwA[B + 1] : dwA[B + 3];
        unsigned int svB0 = hi ? dwB[B + 0] : dwB[B + 2];
        unsigned int svB1 = hi ? dwB[B + 1] : dwB[B + 3];
        unsigned int rvA0 = (unsigned int)__shfl_xor((int)svA0, 32);
        unsigned int rvA1 = (unsigned int)__shfl_xor((int)svA1, 32);
        unsigned int rvB0 = (unsigned int)__shfl_xor((int)svB0, 32);
        unsigned int rvB1 = (unsigned int)__shfl_xor((int)svB1, 32);
        union { unsigned int d[4]; bf16x8 v; } puA, puB;
        puA.d[0] = hi ? rvA0 : dwA[B + 0];
        puA.d[1] = hi ? rvA1 : dwA[B + 1];
        puA.d[2] = hi ? dwA[B + 2] : rvA0;
        puA.d[3] = hi ? dwA[B + 3] : rvA1;
        puB.d[0] = hi ? rvB0 : dwB[B + 0];
        puB.d[1] = hi ? rvB1 : dwB[B + 1];
        puB.d[2] = hi ? dwB[B + 2] : rvB0;
        puB.d[3] = hi ? dwB[B + 3] : rvB1;
        int cb = (ph * 2 + kk) * 32 + hi * 16;
        bf16x8 v0 = *(const bf16x8*)(vb_ + lq * 128 + (cb ^ swz));
        bf16x8 v1 = *(const bf16x8*)(vb_ + (32 + lq) * 128 + (cb ^ swz));
        accA0 = __builtin_amdgcn_mfma_f32_32x32x16_bf16(v0, puA.v, accA0, 0, 0, 0);
        accA1 = __builtin_amdgcn_mfma_f32_32x32x16_bf16(v1, puA.v, accA1, 0, 0, 0);
        accB0 = __builtin_amdgcn_mfma_f32_32x32x16_bf16(v0, puB.v, accB0, 0, 0, 0);
        accB1 = __builtin_amdgcn_mfma_f32_32x32x16_bf16(v1, puB.v, accB1, 0, 0, 0);
      }
      __builtin_amdgcn_s_setprio(0);
    }
    __syncthreads();
  }

  // ---- epilogue: write bf16 partials for both q-frags ----
  float lsumA = lA + __shfl_xor(lA, 32);
  float lsumB = lB + __shfl_xor(lB, 32);
  size_t qrowA = (size_t)(quarter * 16 + bh) * NSEQ + q0 + lq;
  size_t qrowB = qrowA + 32;
  if (hi == 0) {
    lpart[qrowA] = lsumA;
    lpart[qrowB] = lsumB;
  }
  unsigned short* obA = opart + qrowA * 64;
  unsigned short* obB = opart + qrowB * 64;
#pragma unroll
  for (int rg = 0; rg < 4; ++rg) {
    unsigned int pa0[2], pa1[2], pb0[2], pb1[2];
    asm("v_cvt_pk_bf16_f32 %0, %1, %2" : "=v"(pa0[0]) : "v"(accA0[4 * rg + 0]), "v"(accA0[4 * rg + 1]));
    asm("v_cvt_pk_bf16_f32 %0, %1, %2" : "=v"(pa0[1]) : "v"(accA0[4 * rg + 2]), "v"(accA0[4 * rg + 3]));
    asm("v_cvt_pk_bf16_f32 %0, %1, %2" : "=v"(pa1[0]) : "v"(accA1[4 * rg + 0]), "v"(accA1[4 * rg + 1]));
    asm("v_cvt_pk_bf16_f32 %0, %1, %2" : "=v"(pa1[1]) : "v"(accA1[4 * rg + 2]), "v"(accA1[4 * rg + 3]));
    asm("v_cvt_pk_bf16_f32 %0, %1, %2" : "=v"(pb0[0]) : "v"(accB0[4 * rg + 0]), "v"(accB0[4 * rg + 1]));
    asm("v_cvt_pk_bf16_f32 %0, %1, %2" : "=v"(pb0[1]) : "v"(accB0[4 * rg + 2]), "v"(accB0[4 * rg + 3]));
    asm("v_cvt_pk_bf16_f32 %0, %1, %2" : "=v"(pb1[0]) : "v"(accB1[4 * rg + 0]), "v"(accB1[4 * rg + 1]));
    asm("v_cvt_pk_bf16_f32 %0, %1, %2" : "=v"(pb1[1]) : "v"(accB1[4 * rg + 2]), "v"(accB1[4 * rg + 3]));
    *(uint2*)(obA + 8 * rg + 4 * hi) = *(uint2*)pa0;
    *(uint2*)(obA + 32 + 8 * rg + 4 * hi) = *(uint2*)pa1;
    *(uint2*)(obB + 8 * rg + 4 * hi) = *(uint2*)pb0;
    *(uint2*)(obB + 32 + 8 * rg + 4 * hi) = *(uint2*)pb1;
  }
}

// ---------------- combine 4 quarters + normalize + inverse RoPE -> ao (bf16) ----------------
__global__ __launch_bounds__(256) void k_combine(const unsigned short* __restrict__ opart,
                                                 const float* __restrict__ lpart,
                                                 const float* __restrict__ cosT,
                                                 const float* __restrict__ sinT,
                                                 unsigned short* __restrict__ ao) {
  int bh = blockIdx.y;
  int b = bh >> 3, h = bh & 7;
  int t = threadIdx.x;
  int q = blockIdx.x * 16 + (t >> 4);
  int d = (t & 15) * 4;
  size_t i0 = (size_t)bh * NSEQ + q;
  const size_t QOFF = (size_t)16 * NSEQ;
  float l = lpart[i0] + lpart[i0 + QOFF] + lpart[i0 + 2 * QOFF] + lpart[i0 + 3 * QOFF];
  float o[4] = {0.f, 0.f, 0.f, 0.f};
#pragma unroll
  for (int p = 0; p < 4; ++p) {
    uint2 u = *(const uint2*)(opart + (i0 + p * QOFF) * 64 + d);
    unsigned int u0 = u.x, u1 = u.y;
    o[0] += bf2f((unsigned short)(u0 & 0xffff));
    o[1] += bf2f((unsigned short)(u0 >> 16));
    o[2] += bf2f((unsigned short)(u1 & 0xffff));
    o[3] += bf2f((unsigned short)(u1 >> 16));
  }
  float inv = 1.0f / l;
  float4 c4 = *(const float4*)(cosT + ((size_t)b * NSEQ + q) * 64 + d);
  float4 s4 = *(const float4*)(sinT + ((size_t)b * NSEQ + q) * 64 + d);
  float yx = o[0] * inv;
  float yy = o[1] * inv;
  float yz = o[2] * inv;
  float yw = o[3] * inv;
  float r0 = yx * c4.x + yy * s4.x;
  float r1 = yy * c4.y - yx * s4.y;
  float r2 = yz * c4.z + yw * s4.z;
  float r3 = yw * c4.w - yz * s4.w;
  unsigned int w0, w1;
  asm("v_cvt_pk_bf16_f32 %0, %1, %2" : "=v"(w0) : "v"(r0), "v"(r1));
  asm("v_cvt_pk_bf16_f32 %0, %1, %2" : "=v"(w1) : "v"(r2), "v"(r3));
  unsigned int uu[2] = {w0, w1};
  *(uint2*)(ao + ((size_t)b * NSEQ + q) * DIM + h * 64 + d) = *(uint2*)uu;
}

extern "C" void kernel_launch(void* const* d_in, const int* in_sizes, int n_in,
                              void* d_out, int out_size, void* d_ws, size_t ws_size,
                              hipStream_t stream) {
  const float* x    = (const float*)d_in[0];
  const float* rot  = (const float*)d_in[1];
  const float* lnw  = (const float*)d_in[2];
  const float* lnb  = (const float*)d_in[3];
  const float* wqkv = (const float*)d_in[4];
  const float* wout = (const float*)d_in[5];
  const float* bout = (const float*)d_in[6];
  float* out = (float*)d_out;

  char* ws = (char*)d_ws;
  const size_t MB = (size_t)1 << 20;
  float* cosT          = (float*)(ws + 0 * MB);        // 2 MB
  float* sinT          = (float*)(ws + 2 * MB);        // 2 MB
  unsigned short* wqkb = (unsigned short*)(ws + 4 * MB);   // 1.5 MB (dead after gemm0)
  unsigned short* wob  = (unsigned short*)(ws + 6 * MB);   // 0.5 MB
  float* lpart         = (float*)(ws + 6 * MB + 512 * 1024); // 1 MB (6.5-7.5)
  unsigned short* xn   = (unsigned short*)(ws + 8 * MB);   // 8 MB (dead after gemm0)
  unsigned short* opart = (unsigned short*)(ws + 8 * MB);  // 32 MB bf16 (8-40, attn -> combine)
  unsigned short* qkv  = (unsigned short*)(ws + 16 * MB);  // 24 MB (dead after rope_split)
  unsigned short* qh   = (unsigned short*)(ws + 40 * MB);  // 8 MB (dead after attn)
  unsigned short* ao   = (unsigned short*)(ws + 40 * MB);  // 8 MB (combine -> gemm1)
  unsigned short* kh   = (unsigned short*)(ws + 48 * MB);  // 8 MB
  unsigned short* vt   = (unsigned short*)(ws + 56 * MB);  // 8 MB

  k_tables<<<(BATCH * NSEQ * 64) / 256, 256, 0, stream>>>(rot, cosT, sinT);
  k_cvt<<<(QKVN * DIM + 255) / 256, 256, 0, stream>>>(wqkv, wqkb, QKVN * DIM);
  k_cvt<<<(DIM * DIM + 255) / 256, 256, 0, stream>>>(wout, wob, DIM * DIM);
  k_ln<<<NROWS / 4, 256, 0, stream>>>(x, lnw, lnb, xn);
  k_gemm<0><<<dim3(NROWS / 128, QKVN / 128), 256, 0, stream>>>(xn, wqkb, qkv, nullptr,
                                                               NROWS, QKVN, DIM);
  k_rope_split<<<dim3(NSEQ / 128, 16), 256, 0, stream>>>(qkv, cosT, sinT, qh, kh, vt);
  k_attn<<<1024, 256, 0, stream>>>(qh, kh, vt, opart, lpart);
  k_combine<<<dim3(NSEQ / 16, 16), 256, 0, stream>>>(opart, lpart, cosT, sinT, ao);
  k_gemm<1><<<dim3(NROWS / 128, DIM / 128), 256, 0, stream>>>(ao, wob, out, bout,
                                                              NROWS, DIM, DIM);
}

// Round 11
// 312.079 us; speedup vs baseline: 1.8635x; 1.8635x over previous
//
#include <hip/hip_runtime.h>
#include <cmath>

typedef short bf16x8 __attribute__((ext_vector_type(8)));
typedef float f32x2 __attribute__((ext_vector_type(2)));
typedef float f32x4 __attribute__((ext_vector_type(4)));
typedef float f32x16 __attribute__((ext_vector_type(16)));

#define NSEQ 4096
#define BATCH 2
#define DIM 512
#define HEADS 8
#define NROWS (BATCH * NSEQ)   // 8192
#define QKVN (3 * DIM)         // 1536

__device__ __forceinline__ unsigned short f2bf(float f) {
  unsigned int u = __float_as_uint(f);
  u += 0x7fffu + ((u >> 16) & 1u);
  return (unsigned short)(u >> 16);
}
__device__ __forceinline__ float bf2f(unsigned short h) {
  return __uint_as_float(((unsigned int)h) << 16);
}
__device__ __forceinline__ void gload16(const unsigned short* g, unsigned short* l) {
  __builtin_amdgcn_global_load_lds((const __attribute__((address_space(1))) unsigned int*)g,
                                   (__attribute__((address_space(3))) unsigned int*)l, 16, 0, 0);
}

// ---------------- cos/sin tables ----------------
__global__ __launch_bounds__(256) void k_tables(const float* __restrict__ rot,
                                                float* __restrict__ cosT,
                                                float* __restrict__ sinT) {
  int i = blockIdx.x * 256 + threadIdx.x;
  float f = rot[i];
  cosT[i] = cosf(f);
  sinT[i] = sinf(f);
}

// ---------------- fp32 -> bf16 weight convert ----------------
__global__ __launch_bounds__(256) void k_cvt(const float* __restrict__ src,
                                             unsigned short* __restrict__ dst, int n) {
  int i = blockIdx.x * 256 + threadIdx.x;
  if (i < n) dst[i] = f2bf(src[i]);
}

// ---------------- LayerNorm: one wave per row ----------------
__global__ __launch_bounds__(256) void k_ln(const float* __restrict__ x,
                                            const float* __restrict__ w,
                                            const float* __restrict__ bb,
                                            unsigned short* __restrict__ xn) {
  int row = blockIdx.x * 4 + (threadIdx.x >> 6);
  int lane = threadIdx.x & 63;
  const float* xr = x + (size_t)row * DIM;
  float v[8];
  float s = 0.f;
#pragma unroll
  for (int j = 0; j < 8; ++j) { v[j] = xr[lane + j * 64]; s += v[j]; }
#pragma unroll
  for (int m = 1; m < 64; m <<= 1) s += __shfl_xor(s, m);
  float mu = s * (1.0f / DIM);
  float q = 0.f;
#pragma unroll
  for (int j = 0; j < 8; ++j) { float d = v[j] - mu; q += d * d; }
#pragma unroll
  for (int m = 1; m < 64; m <<= 1) q += __shfl_xor(q, m);
  float rs = rsqrtf(q * (1.0f / DIM) + 1e-5f);
#pragma unroll
  for (int j = 0; j < 8; ++j) {
    int col = lane + j * 64;
    xn[(size_t)row * DIM + col] = f2bf((v[j] - mu) * rs * w[col] + bb[col]);
  }
}

// ---------------- GEMM: C[M][N] = A[M][K] * B[N][K]^T (dbuf, 1 barrier/step) ----------------
template <int EPI>
__global__ __launch_bounds__(256) void k_gemm(const unsigned short* __restrict__ A,
                                              const unsigned short* __restrict__ B,
                                              void* __restrict__ C,
                                              const float* __restrict__ bias,
                                              int M, int N, int K) {
  __shared__ __align__(16) unsigned short As[2][128 * 32];
  __shared__ __align__(16) unsigned short Bs[2][128 * 32];
  int bm = blockIdx.x, bn = blockIdx.y;
  int tid = threadIdx.x;
  int lane = tid & 63, w = tid >> 6;
  int wm = (w >> 1) << 6, wn = (w & 1) << 6;
  f32x4 acc[4][4] = {};

#define GSTAGE(KT, BUF) do { \
  _Pragma("unroll") \
  for (int i = 0; i < 2; ++i) { \
    int c = tid + (i << 8); \
    int row = c >> 2, kc = (c & 3) << 3; \
    gload16(A + (size_t)(bm * 128 + row) * K + (KT) + kc, &As[BUF][(w * 64 + i * 256) * 8]); \
    gload16(B + (size_t)(bn * 128 + row) * K + (KT) + kc, &Bs[BUF][(w * 64 + i * 256) * 8]); \
  } } while (0)

  GSTAGE(0, 0);
  __syncthreads();
  int nk = K >> 5;
  for (int t = 0; t < nk; ++t) {
    int cur = t & 1;
    if (t + 1 < nk) GSTAGE((t + 1) << 5, cur ^ 1);
    bf16x8 af[4], bfr[4];
#pragma unroll
    for (int mi = 0; mi < 4; ++mi)
      af[mi] = *(const bf16x8*)&As[cur][(wm + mi * 16 + (lane & 15)) * 32 + ((lane >> 4) << 3)];
#pragma unroll
    for (int ni = 0; ni < 4; ++ni)
      bfr[ni] = *(const bf16x8*)&Bs[cur][(wn + ni * 16 + (lane & 15)) * 32 + ((lane >> 4) << 3)];
#pragma unroll
    for (int mi = 0; mi < 4; ++mi)
#pragma unroll
      for (int ni = 0; ni < 4; ++ni)
        acc[mi][ni] = __builtin_amdgcn_mfma_f32_16x16x32_bf16(af[mi], bfr[ni], acc[mi][ni], 0, 0, 0);
    __syncthreads();
  }
#undef GSTAGE
#pragma unroll
  for (int mi = 0; mi < 4; ++mi) {
#pragma unroll
    for (int ni = 0; ni < 4; ++ni) {
#pragma unroll
      for (int r = 0; r < 4; ++r) {
        int gm = bm * 128 + wm + mi * 16 + ((lane >> 4) << 2) + r;
        int gn = bn * 128 + wn + ni * 16 + (lane & 15);
        if (EPI == 0) {
          ((unsigned short*)C)[(size_t)gm * N + gn] = f2bf(acc[mi][ni][r]);
        } else {
          ((float*)C)[(size_t)gm * N + gn] = acc[mi][ni][r] + bias[gn];
        }
      }
    }
  }
}

// ------ RoPE + head split (+ V transpose); Q pre-scaled by 0.125*log2(e) (exp2-domain) ------
__global__ __launch_bounds__(256) void k_rope_split(const unsigned short* __restrict__ qkv,
                                                    const float* __restrict__ cosT,
                                                    const float* __restrict__ sinT,
                                                    unsigned short* __restrict__ qh,
                                                    unsigned short* __restrict__ kh,
                                                    unsigned short* __restrict__ vt) {
  __shared__ unsigned short vs[128][65];
  const float QSC = 0.125f * 1.44269504f;
  int nt = blockIdx.x, bh = blockIdx.y;
  int b = bh >> 3, h = bh & 7;
  int n0 = nt * 128;
  int t = threadIdx.x;
  int sub = t >> 3, cc = t & 7;
#pragma unroll
  for (int rr = 0; rr < 4; ++rr) {
    int row = rr * 32 + sub;
    int n = n0 + row;
    size_t base = ((size_t)(b * NSEQ + n)) * QKVN + h * 64 + cc * 8;
    const float* cb = cosT + ((size_t)(b * NSEQ + n)) * 64 + cc * 8;
    const float* sb = sinT + ((size_t)(b * NSEQ + n)) * 64 + cc * 8;
    float c[8], sn[8];
#pragma unroll
    for (int j = 0; j < 8; ++j) { c[j] = cb[j]; sn[j] = sb[j]; }
    bf16x8 qv = *(const bf16x8*)(qkv + base);
    bf16x8 kv = *(const bf16x8*)(qkv + base + 512);
    bf16x8 vv = *(const bf16x8*)(qkv + base + 1024);
    union { bf16x8 v; unsigned short u[8]; } yq, yk;
#pragma unroll
    for (int j = 0; j < 8; j += 2) {
      {
        float e = bf2f((unsigned short)qv[j]), o = bf2f((unsigned short)qv[j + 1]);
        yq.u[j]     = f2bf((e * c[j] - o * sn[j]) * QSC);
        yq.u[j + 1] = f2bf((o * c[j + 1] + e * sn[j + 1]) * QSC);
      }
      {
        float e = bf2f((unsigned short)kv[j]), o = bf2f((unsigned short)kv[j + 1]);
        yk.u[j]     = f2bf(e * c[j] - o * sn[j]);
        yk.u[j + 1] = f2bf(o * c[j + 1] + e * sn[j + 1]);
      }
      {
        float e = bf2f((unsigned short)vv[j]), o = bf2f((unsigned short)vv[j + 1]);
        vs[row][cc * 8 + j]     = f2bf(e * c[j] - o * sn[j]);
        vs[row][cc * 8 + j + 1] = f2bf(o * c[j + 1] + e * sn[j + 1]);
      }
    }
    *(bf16x8*)(qh + ((size_t)bh * NSEQ + n) * 64 + cc * 8) = yq.v;
    *(bf16x8*)(kh + ((size_t)bh * NSEQ + n) * 64 + cc * 8) = yk.v;
  }
  __syncthreads();
  int d = t >> 2, c4 = t & 3;
#pragma unroll
  for (int g = 0; g < 4; ++g) {
    union { bf16x8 v; unsigned short u[8]; } tv;
#pragma unroll
    for (int j = 0; j < 8; ++j) tv.u[j] = vs[c4 * 32 + g * 8 + j][d];
    *(bf16x8*)(vt + ((size_t)bh * 64 + d) * NSEQ + n0 + c4 * 32 + g * 8) = tv.v;
  }
}

// ---------------- Flash attention v11: KV-split-4, 64q/wave, bf16 partials ----
// Identical to round-10 body; ONLY change: launch_bounds (256,4) -> (256,3).
// (256,4) capped regs at 128 < ~172 needed -> hot accumulator spill (2.4 GB scratch
// traffic, 512 us). (256,3) caps at 170 -> at most a couple of cold spills, and
// grid 1024 delivers 3 blocks/CU (12 waves/CU) vs round 9's grid-limited 2.
__global__ __launch_bounds__(256, 3) void k_attn(const unsigned short* __restrict__ Qh,
                                                 const unsigned short* __restrict__ Kh,
                                                 const unsigned short* __restrict__ VT,
                                                 unsigned short* __restrict__ opart,
                                                 float* __restrict__ lpart) {
  __shared__ __align__(16) unsigned short Ks[2][64 * 64];
  __shared__ __align__(16) unsigned short Vs[2][64 * 64];
  int bid = blockIdx.x;
  int bh   = (bid & 7) + 8 * ((bid >> 7) & 1);  // XCD-pinned: bh%8 == bid%8
  int qt   = (bid >> 3) & 15;
  int quarter = (bid >> 8) & 3;
  int tid = threadIdx.x;
  int w = tid >> 6, lane = tid & 63;
  int lq = lane & 31, hi = lane >> 5;
  int q0 = qt * 256 + w * 64;
  int kv0 = quarter << 10;

  const unsigned short* Kbh = Kh + (size_t)bh * NSEQ * 64;
  const unsigned short* Vbh = VT + (size_t)bh * 64 * NSEQ;

  const unsigned short* QbA = Qh + ((size_t)bh * NSEQ + q0 + lq) * 64 + hi * 8;
  const unsigned short* QbB = QbA + 32 * 64;
  bf16x8 qfA[4], qfB[4];
#pragma unroll
  for (int j = 0; j < 4; ++j) {
    qfA[j] = *(const bf16x8*)(QbA + j * 16);
    qfB[j] = *(const bf16x8*)(QbB + j * 16);
  }

  // staging chunk geometry: chunk c -> row r=c>>3, source 16B slot (c&7)^(r&7)
  int c0 = w * 64 + lane;
  int r0 = c0 >> 3, sw0 = ((c0 & 7) ^ (r0 & 7)) << 3;
  int c1 = c0 + 256;
  int r1 = c1 >> 3, sw1 = ((c1 & 7) ^ (r1 & 7)) << 3;
  int ld0 = (w * 64) * 8, ld1 = (256 + w * 64) * 8;

  f32x16 accA0 = (f32x16)0.0f, accA1 = (f32x16)0.0f;
  f32x16 accB0 = (f32x16)0.0f, accB1 = (f32x16)0.0f;
  float lA = 0.f, lB = 0.f;
  int swz = (lq & 7) << 4;

  // prologue: stage tile 0 into buf 0
  gload16(Kbh + ((size_t)kv0 + r0) * 64 + sw0, &Ks[0][ld0]);
  gload16(Kbh + ((size_t)kv0 + r1) * 64 + sw1, &Ks[0][ld1]);
  gload16(Vbh + (size_t)r0 * NSEQ + kv0 + sw0, &Vs[0][ld0]);
  gload16(Vbh + (size_t)r1 * NSEQ + kv0 + sw1, &Vs[0][ld1]);
  __syncthreads();

  for (int t = 0; t < 16; ++t) {
    int cur = t & 1;
    if (t < 15) {
      int tg = kv0 + (t + 1) * 64;
      gload16(Kbh + ((size_t)tg + r0) * 64 + sw0, &Ks[cur ^ 1][ld0]);
      gload16(Kbh + ((size_t)tg + r1) * 64 + sw1, &Ks[cur ^ 1][ld1]);
      gload16(Vbh + (size_t)r0 * NSEQ + tg + sw0, &Vs[cur ^ 1][ld0]);
      gload16(Vbh + (size_t)r1 * NSEQ + tg + sw1, &Vs[cur ^ 1][ld1]);
    }
    const char* kb_ = (const char*)&Ks[cur][0];
    const char* vb_ = (const char*)&Vs[cur][0];
#pragma unroll
    for (int ph = 0; ph < 2; ++ph) {
      // ---- QK^T: 32 k-rows x 64 q (each a-read feeds both q-frags) ----
      f32x16 sA = (f32x16)0.0f, sB = (f32x16)0.0f;
      __builtin_amdgcn_s_setprio(1);
#pragma unroll
      for (int j = 0; j < 4; ++j) {
        int cb = j * 32 + hi * 16;
        bf16x8 a = *(const bf16x8*)(kb_ + (ph * 32 + lq) * 128 + (cb ^ swz));
        sA = __builtin_amdgcn_mfma_f32_32x32x16_bf16(a, qfA[j], sA, 0, 0, 0);
        sB = __builtin_amdgcn_mfma_f32_32x32x16_bf16(a, qfB[j], sB, 0, 0, 0);
      }
      __builtin_amdgcn_s_setprio(0);
      // ---- exp2 (raw) + packed sums ----
#pragma unroll
      for (int r = 0; r < 16; ++r) sA[r] = __builtin_amdgcn_exp2f(sA[r]);
#pragma unroll
      for (int r = 0; r < 16; ++r) sB[r] = __builtin_amdgcn_exp2f(sB[r]);
      {
        union { f32x16 v; f32x2 p[8]; } ua, ub; ua.v = sA; ub.v = sB;
        f32x2 a01 = ua.p[0] + ua.p[1], a23 = ua.p[2] + ua.p[3];
        f32x2 a45 = ua.p[4] + ua.p[5], a67 = ua.p[6] + ua.p[7];
        f32x2 ta = (a01 + a23) + (a45 + a67);
        lA += ta.x + ta.y;
        f32x2 b01 = ub.p[0] + ub.p[1], b23 = ub.p[2] + ub.p[3];
        f32x2 b45 = ub.p[4] + ub.p[5], b67 = ub.p[6] + ub.p[7];
        f32x2 tb = (b01 + b23) + (b45 + b67);
        lB += tb.x + tb.y;
      }
      // ---- pack P -> bf16 ----
      unsigned int dwA[8], dwB[8];
#pragma unroll
      for (int m = 0; m < 8; ++m) {
        asm("v_cvt_pk_bf16_f32 %0, %1, %2" : "=v"(dwA[m]) : "v"(sA[2 * m]), "v"(sA[2 * m + 1]));
        asm("v_cvt_pk_bf16_f32 %0, %1, %2" : "=v"(dwB[m]) : "v"(sB[2 * m]), "v"(sB[2 * m + 1]));
      }
      // ---- PV: each v-read feeds both q-frags; exchange via shfl_xor (proven) ----
      __builtin_amdgcn_s_setprio(1);
#pragma unroll
      for (int kk = 0; kk < 2; ++kk) {
        const int B = 4 * kk;
        unsigned int svA0 = hi ? dwA[B + 0] : dwA[B + 2];
        unsigned int svA1 = hi ? dwA[B + 1] : dwA[B + 3];
        unsigned int svB0 = hi ? dwB[B + 0] : dwB[B + 2];
        unsigned int svB1 = hi ? dwB[B + 1] : dwB[B + 3];
        unsigned int rvA0 = (unsigned int)__shfl_xor((int)svA0, 32);
        unsigned int rvA1 = (unsigned int)__shfl_xor((int)svA1, 32);
        unsigned int rvB0 = (unsigned int)__shfl_xor((int)svB0, 32);
        unsigned int rvB1 = (unsigned int)__shfl_xor((int)svB1, 32);
        union { unsigned int d[4]; bf16x8 v; } puA, puB;
        puA.d[0] = hi ? rvA0 : dwA[B + 0];
        puA.d[1] = hi ? rvA1 : dwA[B + 1];
        puA.d[2] = hi ? dwA[B + 2] : rvA0;
        puA.d[3] = hi ? dwA[B + 3] : rvA1;
        puB.d[0] = hi ? rvB0 : dwB[B + 0];
        puB.d[1] = hi ? rvB1 : dwB[B + 1];
        puB.d[2] = hi ? dwB[B + 2] : rvB0;
        puB.d[3] = hi ? dwB[B + 3] : rvB1;
        int cb = (ph * 2 + kk) * 32 + hi * 16;
        bf16x8 v0 = *(const bf16x8*)(vb_ + lq * 128 + (cb ^ swz));
        bf16x8 v1 = *(const bf16x8*)(vb_ + (32 + lq) * 128 + (cb ^ swz));
        accA0 = __builtin_amdgcn_mfma_f32_32x32x16_bf16(v0, puA.v, accA0, 0, 0, 0);
        accA1 = __builtin_amdgcn_mfma_f32_32x32x16_bf16(v1, puA.v, accA1, 0, 0, 0);
        accB0 = __builtin_amdgcn_mfma_f32_32x32x16_bf16(v0, puB.v, accB0, 0, 0, 0);
        accB1 = __builtin_amdgcn_mfma_f32_32x32x16_bf16(v1, puB.v, accB1, 0, 0, 0);
      }
      __builtin_amdgcn_s_setprio(0);
    }
    __syncthreads();
  }

  // ---- epilogue: write bf16 partials for both q-frags ----
  float lsumA = lA + __shfl_xor(lA, 32);
  float lsumB = lB + __shfl_xor(lB, 32);
  size_t qrowA = (size_t)(quarter * 16 + bh) * NSEQ + q0 + lq;
  size_t qrowB = qrowA + 32;
  if (hi == 0) {
    lpart[qrowA] = lsumA;
    lpart[qrowB] = lsumB;
  }
  unsigned short* obA = opart + qrowA * 64;
  unsigned short* obB = opart + qrowB * 64;
#pragma unroll
  for (int rg = 0; rg < 4; ++rg) {
    unsigned int pa0[2], pa1[2], pb0[2], pb1[2];
    asm("v_cvt_pk_bf16_f32 %0, %1, %2" : "=v"(pa0[0]) : "v"(accA0[4 * rg + 0]), "v"(accA0[4 * rg + 1]));
    asm("v_cvt_pk_bf16_f32 %0, %1, %2" : "=v"(pa0[1]) : "v"(accA0[4 * rg + 2]), "v"(accA0[4 * rg + 3]));
    asm("v_cvt_pk_bf16_f32 %0, %1, %2" : "=v"(pa1[0]) : "v"(accA1[4 * rg + 0]), "v"(accA1[4 * rg + 1]));
    asm("v_cvt_pk_bf16_f32 %0, %1, %2" : "=v"(pa1[1]) : "v"(accA1[4 * rg + 2]), "v"(accA1[4 * rg + 3]));
    asm("v_cvt_pk_bf16_f32 %0, %1, %2" : "=v"(pb0[0]) : "v"(accB0[4 * rg + 0]), "v"(accB0[4 * rg + 1]));
    asm("v_cvt_pk_bf16_f32 %0, %1, %2" : "=v"(pb0[1]) : "v"(accB0[4 * rg + 2]), "v"(accB0[4 * rg + 3]));
    asm("v_cvt_pk_bf16_f32 %0, %1, %2" : "=v"(pb1[0]) : "v"(accB1[4 * rg + 0]), "v"(accB1[4 * rg + 1]));
    asm("v_cvt_pk_bf16_f32 %0, %1, %2" : "=v"(pb1[1]) : "v"(accB1[4 * rg + 2]), "v"(accB1[4 * rg + 3]));
    *(uint2*)(obA + 8 * rg + 4 * hi) = *(uint2*)pa0;
    *(uint2*)(obA + 32 + 8 * rg + 4 * hi) = *(uint2*)pa1;
    *(uint2*)(obB + 8 * rg + 4 * hi) = *(uint2*)pb0;
    *(uint2*)(obB + 32 + 8 * rg + 4 * hi) = *(uint2*)pb1;
  }
}

// ---------------- combine 4 quarters + normalize + inverse RoPE -> ao (bf16) ----------------
__global__ __launch_bounds__(256) void k_combine(const unsigned short* __restrict__ opart,
                                                 const float* __restrict__ lpart,
                                                 const float* __restrict__ cosT,
                                                 const float* __restrict__ sinT,
                                                 unsigned short* __restrict__ ao) {
  int bh = blockIdx.y;
  int b = bh >> 3, h = bh & 7;
  int t = threadIdx.x;
  int q = blockIdx.x * 16 + (t >> 4);
  int d = (t & 15) * 4;
  size_t i0 = (size_t)bh * NSEQ + q;
  const size_t QOFF = (size_t)16 * NSEQ;
  float l = lpart[i0] + lpart[i0 + QOFF] + lpart[i0 + 2 * QOFF] + lpart[i0 + 3 * QOFF];
  float o[4] = {0.f, 0.f, 0.f, 0.f};
#pragma unroll
  for (int p = 0; p < 4; ++p) {
    uint2 u = *(const uint2*)(opart + (i0 + p * QOFF) * 64 + d);
    unsigned int u0 = u.x, u1 = u.y;
    o[0] += bf2f((unsigned short)(u0 & 0xffff));
    o[1] += bf2f((unsigned short)(u0 >> 16));
    o[2] += bf2f((unsigned short)(u1 & 0xffff));
    o[3] += bf2f((unsigned short)(u1 >> 16));
  }
  float inv = 1.0f / l;
  float4 c4 = *(const float4*)(cosT + ((size_t)b * NSEQ + q) * 64 + d);
  float4 s4 = *(const float4*)(sinT + ((size_t)b * NSEQ + q) * 64 + d);
  float yx = o[0] * inv;
  float yy = o[1] * inv;
  float yz = o[2] * inv;
  float yw = o[3] * inv;
  float r0 = yx * c4.x + yy * s4.x;
  float r1 = yy * c4.y - yx * s4.y;
  float r2 = yz * c4.z + yw * s4.z;
  float r3 = yw * c4.w - yz * s4.w;
  unsigned int w0, w1;
  asm("v_cvt_pk_bf16_f32 %0, %1, %2" : "=v"(w0) : "v"(r0), "v"(r1));
  asm("v_cvt_pk_bf16_f32 %0, %1, %2" : "=v"(w1) : "v"(r2), "v"(r3));
  unsigned int uu[2] = {w0, w1};
  *(uint2*)(ao + ((size_t)b * NSEQ + q) * DIM + h * 64 + d) = *(uint2*)uu;
}

extern "C" void kernel_launch(void* const* d_in, const int* in_sizes, int n_in,
                              void* d_out, int out_size, void* d_ws, size_t ws_size,
                              hipStream_t stream) {
  const float* x    = (const float*)d_in[0];
  const float* rot  = (const float*)d_in[1];
  const float* lnw  = (const float*)d_in[2];
  const float* lnb  = (const float*)d_in[3];
  const float* wqkv = (const float*)d_in[4];
  const float* wout = (const float*)d_in[5];
  const float* bout = (const float*)d_in[6];
  float* out = (float*)d_out;

  char* ws = (char*)d_ws;
  const size_t MB = (size_t)1 << 20;
  float* cosT          = (float*)(ws + 0 * MB);        // 2 MB
  float* sinT          = (float*)(ws + 2 * MB);        // 2 MB
  unsigned short* wqkb = (unsigned short*)(ws + 4 * MB);   // 1.5 MB (dead after gemm0)
  unsigned short* wob  = (unsigned short*)(ws + 6 * MB);   // 0.5 MB
  float* lpart         = (float*)(ws + 6 * MB + 512 * 1024); // 1 MB (6.5-7.5)
  unsigned short* xn   = (unsigned short*)(ws + 8 * MB);   // 8 MB (dead after gemm0)
  unsigned short* opart = (unsigned short*)(ws + 8 * MB);  // 32 MB bf16 (8-40, attn -> combine)
  unsigned short* qkv  = (unsigned short*)(ws + 16 * MB);  // 24 MB (dead after rope_split)
  unsigned short* qh   = (unsigned short*)(ws + 40 * MB);  // 8 MB (dead after attn)
  unsigned short* ao   = (unsigned short*)(ws + 40 * MB);  // 8 MB (combine -> gemm1)
  unsigned short* kh   = (unsigned short*)(ws + 48 * MB);  // 8 MB
  unsigned short* vt   = (unsigned short*)(ws + 56 * MB);  // 8 MB

  k_tables<<<(BATCH * NSEQ * 64) / 256, 256, 0, stream>>>(rot, cosT, sinT);
  k_cvt<<<(QKVN * DIM + 255) / 256, 256, 0, stream>>>(wqkv, wqkb, QKVN * DIM);
  k_cvt<<<(DIM * DIM + 255) / 256, 256, 0, stream>>>(wout, wob, DIM * DIM);
  k_ln<<<NROWS / 4, 256, 0, stream>>>(x, lnw, lnb, xn);
  k_gemm<0><<<dim3(NROWS / 128, QKVN / 128), 256, 0, stream>>>(xn, wqkb, qkv, nullptr,
                                                               NROWS, QKVN, DIM);
  k_rope_split<<<dim3(NSEQ / 128, 16), 256, 0, stream>>>(qkv, cosT, sinT, qh, kh, vt);
  k_attn<<<1024, 256, 0, stream>>>(qh, kh, vt, opart, lpart);
  k_combine<<<dim3(NSEQ / 16, 16), 256, 0, stream>>>(opart, lpart, cosT, sinT, ao);
  k_gemm<1><<<dim3(NROWS / 128, DIM / 128), 256, 0, stream>>>(ao, wob, out, bout,
                                                              NROWS, DIM, DIM);
}

// Round 12
// 147.368 us; speedup vs baseline: 3.9462x; 2.1177x over previous
//
#include <hip/hip_runtime.h>
#include <cmath>

typedef short bf16x8 __attribute__((ext_vector_type(8)));
typedef float f32x2 __attribute__((ext_vector_type(2)));
typedef float f32x4 __attribute__((ext_vector_type(4)));
typedef float f32x16 __attribute__((ext_vector_type(16)));

#define NSEQ 4096
#define BATCH 2
#define DIM 512
#define HEADS 8
#define NROWS (BATCH * NSEQ)   // 8192
#define QKVN (3 * DIM)         // 1536

__device__ __forceinline__ unsigned short f2bf(float f) {
  unsigned int u = __float_as_uint(f);
  u += 0x7fffu + ((u >> 16) & 1u);
  return (unsigned short)(u >> 16);
}
__device__ __forceinline__ float bf2f(unsigned short h) {
  return __uint_as_float(((unsigned int)h) << 16);
}
__device__ __forceinline__ void gload16(const unsigned short* g, unsigned short* l) {
  __builtin_amdgcn_global_load_lds((const __attribute__((address_space(1))) unsigned int*)g,
                                   (__attribute__((address_space(3))) unsigned int*)l, 16, 0, 0);
}

// ---------------- cos/sin tables ----------------
__global__ __launch_bounds__(256) void k_tables(const float* __restrict__ rot,
                                                float* __restrict__ cosT,
                                                float* __restrict__ sinT) {
  int i = blockIdx.x * 256 + threadIdx.x;
  float f = rot[i];
  cosT[i] = cosf(f);
  sinT[i] = sinf(f);
}

// ---------------- fp32 -> bf16 weight convert ----------------
__global__ __launch_bounds__(256) void k_cvt(const float* __restrict__ src,
                                             unsigned short* __restrict__ dst, int n) {
  int i = blockIdx.x * 256 + threadIdx.x;
  if (i < n) dst[i] = f2bf(src[i]);
}

// ---------------- LayerNorm: one wave per row ----------------
__global__ __launch_bounds__(256) void k_ln(const float* __restrict__ x,
                                            const float* __restrict__ w,
                                            const float* __restrict__ bb,
                                            unsigned short* __restrict__ xn) {
  int row = blockIdx.x * 4 + (threadIdx.x >> 6);
  int lane = threadIdx.x & 63;
  const float* xr = x + (size_t)row * DIM;
  float v[8];
  float s = 0.f;
#pragma unroll
  for (int j = 0; j < 8; ++j) { v[j] = xr[lane + j * 64]; s += v[j]; }
#pragma unroll
  for (int m = 1; m < 64; m <<= 1) s += __shfl_xor(s, m);
  float mu = s * (1.0f / DIM);
  float q = 0.f;
#pragma unroll
  for (int j = 0; j < 8; ++j) { float d = v[j] - mu; q += d * d; }
#pragma unroll
  for (int m = 1; m < 64; m <<= 1) q += __shfl_xor(q, m);
  float rs = rsqrtf(q * (1.0f / DIM) + 1e-5f);
#pragma unroll
  for (int j = 0; j < 8; ++j) {
    int col = lane + j * 64;
    xn[(size_t)row * DIM + col] = f2bf((v[j] - mu) * rs * w[col] + bb[col]);
  }
}

// ---------------- GEMM: C[M][N] = A[M][K] * B[N][K]^T (dbuf, 1 barrier/step) ----------------
template <int EPI>
__global__ __launch_bounds__(256) void k_gemm(const unsigned short* __restrict__ A,
                                              const unsigned short* __restrict__ B,
                                              void* __restrict__ C,
                                              const float* __restrict__ bias,
                                              int M, int N, int K) {
  __shared__ __align__(16) unsigned short As[2][128 * 32];
  __shared__ __align__(16) unsigned short Bs[2][128 * 32];
  int bm = blockIdx.x, bn = blockIdx.y;
  int tid = threadIdx.x;
  int lane = tid & 63, w = tid >> 6;
  int wm = (w >> 1) << 6, wn = (w & 1) << 6;
  f32x4 acc[4][4] = {};

#define GSTAGE(KT, BUF) do { \
  _Pragma("unroll") \
  for (int i = 0; i < 2; ++i) { \
    int c = tid + (i << 8); \
    int row = c >> 2, kc = (c & 3) << 3; \
    gload16(A + (size_t)(bm * 128 + row) * K + (KT) + kc, &As[BUF][(w * 64 + i * 256) * 8]); \
    gload16(B + (size_t)(bn * 128 + row) * K + (KT) + kc, &Bs[BUF][(w * 64 + i * 256) * 8]); \
  } } while (0)

  GSTAGE(0, 0);
  __syncthreads();
  int nk = K >> 5;
  for (int t = 0; t < nk; ++t) {
    int cur = t & 1;
    if (t + 1 < nk) GSTAGE((t + 1) << 5, cur ^ 1);
    bf16x8 af[4], bfr[4];
#pragma unroll
    for (int mi = 0; mi < 4; ++mi)
      af[mi] = *(const bf16x8*)&As[cur][(wm + mi * 16 + (lane & 15)) * 32 + ((lane >> 4) << 3)];
#pragma unroll
    for (int ni = 0; ni < 4; ++ni)
      bfr[ni] = *(const bf16x8*)&Bs[cur][(wn + ni * 16 + (lane & 15)) * 32 + ((lane >> 4) << 3)];
#pragma unroll
    for (int mi = 0; mi < 4; ++mi)
#pragma unroll
      for (int ni = 0; ni < 4; ++ni)
        acc[mi][ni] = __builtin_amdgcn_mfma_f32_16x16x32_bf16(af[mi], bfr[ni], acc[mi][ni], 0, 0, 0);
    __syncthreads();
  }
#undef GSTAGE
#pragma unroll
  for (int mi = 0; mi < 4; ++mi) {
#pragma unroll
    for (int ni = 0; ni < 4; ++ni) {
#pragma unroll
      for (int r = 0; r < 4; ++r) {
        int gm = bm * 128 + wm + mi * 16 + ((lane >> 4) << 2) + r;
        int gn = bn * 128 + wn + ni * 16 + (lane & 15);
        if (EPI == 0) {
          ((unsigned short*)C)[(size_t)gm * N + gn] = f2bf(acc[mi][ni][r]);
        } else {
          ((float*)C)[(size_t)gm * N + gn] = acc[mi][ni][r] + bias[gn];
        }
      }
    }
  }
}

// ------ RoPE + head split (+ V transpose); Q pre-scaled by 0.125*log2(e) (exp2-domain) ------
__global__ __launch_bounds__(256) void k_rope_split(const unsigned short* __restrict__ qkv,
                                                    const float* __restrict__ cosT,
                                                    const float* __restrict__ sinT,
                                                    unsigned short* __restrict__ qh,
                                                    unsigned short* __restrict__ kh,
                                                    unsigned short* __restrict__ vt) {
  __shared__ unsigned short vs[128][65];
  const float QSC = 0.125f * 1.44269504f;
  int nt = blockIdx.x, bh = blockIdx.y;
  int b = bh >> 3, h = bh & 7;
  int n0 = nt * 128;
  int t = threadIdx.x;
  int sub = t >> 3, cc = t & 7;
#pragma unroll
  for (int rr = 0; rr < 4; ++rr) {
    int row = rr * 32 + sub;
    int n = n0 + row;
    size_t base = ((size_t)(b * NSEQ + n)) * QKVN + h * 64 + cc * 8;
    const float* cb = cosT + ((size_t)(b * NSEQ + n)) * 64 + cc * 8;
    const float* sb = sinT + ((size_t)(b * NSEQ + n)) * 64 + cc * 8;
    float c[8], sn[8];
#pragma unroll
    for (int j = 0; j < 8; ++j) { c[j] = cb[j]; sn[j] = sb[j]; }
    bf16x8 qv = *(const bf16x8*)(qkv + base);
    bf16x8 kv = *(const bf16x8*)(qkv + base + 512);
    bf16x8 vv = *(const bf16x8*)(qkv + base + 1024);
    union { bf16x8 v; unsigned short u[8]; } yq, yk;
#pragma unroll
    for (int j = 0; j < 8; j += 2) {
      {
        float e = bf2f((unsigned short)qv[j]), o = bf2f((unsigned short)qv[j + 1]);
        yq.u[j]     = f2bf((e * c[j] - o * sn[j]) * QSC);
        yq.u[j + 1] = f2bf((o * c[j + 1] + e * sn[j + 1]) * QSC);
      }
      {
        float e = bf2f((unsigned short)kv[j]), o = bf2f((unsigned short)kv[j + 1]);
        yk.u[j]     = f2bf(e * c[j] - o * sn[j]);
        yk.u[j + 1] = f2bf(o * c[j + 1] + e * sn[j + 1]);
      }
      {
        float e = bf2f((unsigned short)vv[j]), o = bf2f((unsigned short)vv[j + 1]);
        vs[row][cc * 8 + j]     = f2bf(e * c[j] - o * sn[j]);
        vs[row][cc * 8 + j + 1] = f2bf(o * c[j + 1] + e * sn[j + 1]);
      }
    }
    *(bf16x8*)(qh + ((size_t)bh * NSEQ + n) * 64 + cc * 8) = yq.v;
    *(bf16x8*)(kh + ((size_t)bh * NSEQ + n) * 64 + cc * 8) = yk.v;
  }
  __syncthreads();
  int d = t >> 2, c4 = t & 3;
#pragma unroll
  for (int g = 0; g < 4; ++g) {
    union { bf16x8 v; unsigned short u[8]; } tv;
#pragma unroll
    for (int j = 0; j < 8; ++j) tv.u[j] = vs[c4 * 32 + g * 8 + j][d];
    *(bf16x8*)(vt + ((size_t)bh * 64 + d) * NSEQ + n0 + c4 * 32 + g * 8) = tv.v;
  }
}

// ---------------- Flash attention v12: round-9 body + counted-vmcnt pipeline ----
// 512 blocks x 4 waves; block = (bh, 256-q tile, KV half of 2048); 64q/wave, 2 q-frags.
// NEW: 4-buffer LDS rotation, depth-2 prefetch, ONE raw s_barrier per tile with
// s_waitcnt vmcnt(8) (never 0 in steady state) -> prefetch stays in flight across
// the barrier (T3/T4; removes the __syncthreads vmcnt(0) drain = per-tile HBM stall).
// Race audit: skew<=1 tile (1 barrier/iter); writer buf[(t+2)&3] vs slowest reader
// buf[t&3] distinct; WAR target last read at t-2 (>=2 barriers). vmcnt(8) leaves
// stages t+1,t+2 (4 loads each) outstanding; waits stage(t). Tail: 4 then 0.
__global__ __launch_bounds__(256, 2) void k_attn(const unsigned short* __restrict__ Qh,
                                                 const unsigned short* __restrict__ Kh,
                                                 const unsigned short* __restrict__ VT,
                                                 float* __restrict__ opart,
                                                 float* __restrict__ lpart) {
  __shared__ __align__(16) unsigned short Ks[4][64 * 64];
  __shared__ __align__(16) unsigned short Vs[4][64 * 64];
  int bid = blockIdx.x;
  int bh   = (bid & 7) + 8 * ((bid >> 7) & 1);  // XCD-pinned: bh%8 == bid%8
  int qt   = (bid >> 3) & 15;
  int half = (bid >> 8) & 1;
  int tid = threadIdx.x;
  int w = tid >> 6, lane = tid & 63;
  int lq = lane & 31, hi = lane >> 5;
  int q0 = qt * 256 + w * 64;
  int kv0 = half * 2048;

  const unsigned short* Kbh = Kh + (size_t)bh * NSEQ * 64;
  const unsigned short* Vbh = VT + (size_t)bh * 64 * NSEQ;

  const unsigned short* QbA = Qh + ((size_t)bh * NSEQ + q0 + lq) * 64 + hi * 8;
  const unsigned short* QbB = QbA + 32 * 64;
  bf16x8 qfA[4], qfB[4];
#pragma unroll
  for (int j = 0; j < 4; ++j) {
    qfA[j] = *(const bf16x8*)(QbA + j * 16);
    qfB[j] = *(const bf16x8*)(QbB + j * 16);
  }

  // staging chunk geometry: chunk c -> row r=c>>3, source 16B slot (c&7)^(r&7)
  int c0 = w * 64 + lane;
  int r0 = c0 >> 3, sw0 = ((c0 & 7) ^ (r0 & 7)) << 3;
  int c1 = c0 + 256;
  int r1 = c1 >> 3, sw1 = ((c1 & 7) ^ (r1 & 7)) << 3;
  int ld0 = (w * 64) * 8, ld1 = (256 + w * 64) * 8;

  f32x16 accA0 = (f32x16)0.0f, accA1 = (f32x16)0.0f;
  f32x16 accB0 = (f32x16)0.0f, accB1 = (f32x16)0.0f;
  float lA = 0.f, lB = 0.f;
  int swz = (lq & 7) << 4;

#define STAGE(T, BUF) do { \
  int tg_ = kv0 + (T) * 64; \
  gload16(Kbh + ((size_t)tg_ + r0) * 64 + sw0, &Ks[BUF][ld0]); \
  gload16(Kbh + ((size_t)tg_ + r1) * 64 + sw1, &Ks[BUF][ld1]); \
  gload16(Vbh + (size_t)r0 * NSEQ + tg_ + sw0, &Vs[BUF][ld0]); \
  gload16(Vbh + (size_t)r1 * NSEQ + tg_ + sw1, &Vs[BUF][ld1]); \
} while (0)

  // prologue: prefetch tiles 0 and 1 (8 loads in flight)
  STAGE(0, 0);
  STAGE(1, 1);

  for (int t = 0; t < 32; ++t) {
    int rd = t & 3;
    if (t < 30) {
      STAGE(t + 2, (t + 2) & 3);
      asm volatile("s_waitcnt vmcnt(8)" ::: "memory");
    } else if (t == 30) {
      asm volatile("s_waitcnt vmcnt(4)" ::: "memory");
    } else {
      asm volatile("s_waitcnt vmcnt(0)" ::: "memory");
    }
    __builtin_amdgcn_s_barrier();
    asm volatile("" ::: "memory");
    const char* kb_ = (const char*)&Ks[rd][0];
    const char* vb_ = (const char*)&Vs[rd][0];
#pragma unroll
    for (int ph = 0; ph < 2; ++ph) {
      // ---- QK^T: 32 k-rows x 64 q (each a-read feeds both q-frags) ----
      f32x16 sA = (f32x16)0.0f, sB = (f32x16)0.0f;
      __builtin_amdgcn_s_setprio(1);
#pragma unroll
      for (int j = 0; j < 4; ++j) {
        int cb = j * 32 + hi * 16;
        bf16x8 a = *(const bf16x8*)(kb_ + (ph * 32 + lq) * 128 + (cb ^ swz));
        sA = __builtin_amdgcn_mfma_f32_32x32x16_bf16(a, qfA[j], sA, 0, 0, 0);
        sB = __builtin_amdgcn_mfma_f32_32x32x16_bf16(a, qfB[j], sB, 0, 0, 0);
      }
      __builtin_amdgcn_s_setprio(0);
      // ---- exp2 (raw) + packed sums ----
#pragma unroll
      for (int r = 0; r < 16; ++r) sA[r] = __builtin_amdgcn_exp2f(sA[r]);
#pragma unroll
      for (int r = 0; r < 16; ++r) sB[r] = __builtin_amdgcn_exp2f(sB[r]);
      {
        union { f32x16 v; f32x2 p[8]; } ua, ub; ua.v = sA; ub.v = sB;
        f32x2 a01 = ua.p[0] + ua.p[1], a23 = ua.p[2] + ua.p[3];
        f32x2 a45 = ua.p[4] + ua.p[5], a67 = ua.p[6] + ua.p[7];
        f32x2 ta = (a01 + a23) + (a45 + a67);
        lA += ta.x + ta.y;
        f32x2 b01 = ub.p[0] + ub.p[1], b23 = ub.p[2] + ub.p[3];
        f32x2 b45 = ub.p[4] + ub.p[5], b67 = ub.p[6] + ub.p[7];
        f32x2 tb = (b01 + b23) + (b45 + b67);
        lB += tb.x + tb.y;
      }
      // ---- pack P -> bf16 ----
      unsigned int dwA[8], dwB[8];
#pragma unroll
      for (int m = 0; m < 8; ++m) {
        asm("v_cvt_pk_bf16_f32 %0, %1, %2" : "=v"(dwA[m]) : "v"(sA[2 * m]), "v"(sA[2 * m + 1]));
        asm("v_cvt_pk_bf16_f32 %0, %1, %2" : "=v"(dwB[m]) : "v"(sB[2 * m]), "v"(sB[2 * m + 1]));
      }
      // ---- PV: each v-read feeds both q-frags; exchange via shfl_xor (proven) ----
      __builtin_amdgcn_s_setprio(1);
#pragma unroll
      for (int kk = 0; kk < 2; ++kk) {
        const int B = 4 * kk;
        unsigned int svA0 = hi ? dwA[B + 0] : dwA[B + 2];
        unsigned int svA1 = hi ? dwA[B + 1] : dwA[B + 3];
        unsigned int svB0 = hi ? dwB[B + 0] : dwB[B + 2];
        unsigned int svB1 = hi ? dwB[B + 1] : dwB[B + 3];
        unsigned int rvA0 = (unsigned int)__shfl_xor((int)svA0, 32);
        unsigned int rvA1 = (unsigned int)__shfl_xor((int)svA1, 32);
        unsigned int rvB0 = (unsigned int)__shfl_xor((int)svB0, 32);
        unsigned int rvB1 = (unsigned int)__shfl_xor((int)svB1, 32);
        union { unsigned int d[4]; bf16x8 v; } puA, puB;
        puA.d[0] = hi ? rvA0 : dwA[B + 0];
        puA.d[1] = hi ? rvA1 : dwA[B + 1];
        puA.d[2] = hi ? dwA[B + 2] : rvA0;
        puA.d[3] = hi ? dwA[B + 3] : rvA1;
        puB.d[0] = hi ? rvB0 : dwB[B + 0];
        puB.d[1] = hi ? rvB1 : dwB[B + 1];
        puB.d[2] = hi ? dwB[B + 2] : rvB0;
        puB.d[3] = hi ? dwB[B + 3] : rvB1;
        int cb = (ph * 2 + kk) * 32 + hi * 16;
        bf16x8 v0 = *(const bf16x8*)(vb_ + lq * 128 + (cb ^ swz));
        bf16x8 v1 = *(const bf16x8*)(vb_ + (32 + lq) * 128 + (cb ^ swz));
        accA0 = __builtin_amdgcn_mfma_f32_32x32x16_bf16(v0, puA.v, accA0, 0, 0, 0);
        accA1 = __builtin_amdgcn_mfma_f32_32x32x16_bf16(v1, puA.v, accA1, 0, 0, 0);
        accB0 = __builtin_amdgcn_mfma_f32_32x32x16_bf16(v0, puB.v, accB0, 0, 0, 0);
        accB1 = __builtin_amdgcn_mfma_f32_32x32x16_bf16(v1, puB.v, accB1, 0, 0, 0);
      }
      __builtin_amdgcn_s_setprio(0);
    }
  }
#undef STAGE

  // ---- epilogue: write raw partials for both q-frags ----
  float lsumA = lA + __shfl_xor(lA, 32);
  float lsumB = lB + __shfl_xor(lB, 32);
  size_t qrowA = (size_t)(half * 16 + bh) * NSEQ + q0 + lq;
  size_t qrowB = qrowA + 32;
  if (hi == 0) {
    lpart[qrowA] = lsumA;
    lpart[qrowB] = lsumB;
  }
  float* obA = opart + qrowA * 64;
  float* obB = opart + qrowB * 64;
#pragma unroll
  for (int rg = 0; rg < 4; ++rg) {
    float4 a0 = make_float4(accA0[4 * rg + 0], accA0[4 * rg + 1], accA0[4 * rg + 2], accA0[4 * rg + 3]);
    float4 a1 = make_float4(accA1[4 * rg + 0], accA1[4 * rg + 1], accA1[4 * rg + 2], accA1[4 * rg + 3]);
    float4 b0 = make_float4(accB0[4 * rg + 0], accB0[4 * rg + 1], accB0[4 * rg + 2], accB0[4 * rg + 3]);
    float4 b1 = make_float4(accB1[4 * rg + 0], accB1[4 * rg + 1], accB1[4 * rg + 2], accB1[4 * rg + 3]);
    *(float4*)(obA + 8 * rg + 4 * hi) = a0;
    *(float4*)(obA + 32 + 8 * rg + 4 * hi) = a1;
    *(float4*)(obB + 8 * rg + 4 * hi) = b0;
    *(float4*)(obB + 32 + 8 * rg + 4 * hi) = b1;
  }
}

// ---------------- combine halves + normalize + inverse RoPE -> ao (bf16) ----------------
__global__ __launch_bounds__(256) void k_combine(const float* __restrict__ opart,
                                                 const float* __restrict__ lpart,
                                                 const float* __restrict__ cosT,
                                                 const float* __restrict__ sinT,
                                                 unsigned short* __restrict__ ao) {
  int bh = blockIdx.y;
  int b = bh >> 3, h = bh & 7;
  int t = threadIdx.x;
  int q = blockIdx.x * 16 + (t >> 4);
  int d = (t & 15) * 4;
  size_t i0 = (size_t)bh * NSEQ + q;
  const size_t HOFF = (size_t)16 * NSEQ;
  float4 o0 = *(const float4*)(opart + i0 * 64 + d);
  float4 o1 = *(const float4*)(opart + (i0 + HOFF) * 64 + d);
  float inv = 1.0f / (lpart[i0] + lpart[i0 + HOFF]);
  float4 c4 = *(const float4*)(cosT + ((size_t)b * NSEQ + q) * 64 + d);
  float4 s4 = *(const float4*)(sinT + ((size_t)b * NSEQ + q) * 64 + d);
  float yx = (o0.x + o1.x) * inv;
  float yy = (o0.y + o1.y) * inv;
  float yz = (o0.z + o1.z) * inv;
  float yw = (o0.w + o1.w) * inv;
  float r0 = yx * c4.x + yy * s4.x;
  float r1 = yy * c4.y - yx * s4.y;
  float r2 = yz * c4.z + yw * s4.z;
  float r3 = yw * c4.w - yz * s4.w;
  unsigned int w0, w1;
  asm("v_cvt_pk_bf16_f32 %0, %1, %2" : "=v"(w0) : "v"(r0), "v"(r1));
  asm("v_cvt_pk_bf16_f32 %0, %1, %2" : "=v"(w1) : "v"(r2), "v"(r3));
  unsigned int uu[2] = {w0, w1};
  *(uint2*)(ao + ((size_t)b * NSEQ + q) * DIM + h * 64 + d) = *(uint2*)uu;
}

extern "C" void kernel_launch(void* const* d_in, const int* in_sizes, int n_in,
                              void* d_out, int out_size, void* d_ws, size_t ws_size,
                              hipStream_t stream) {
  const float* x    = (const float*)d_in[0];
  const float* rot  = (const float*)d_in[1];
  const float* lnw  = (const float*)d_in[2];
  const float* lnb  = (const float*)d_in[3];
  const float* wqkv = (const float*)d_in[4];
  const float* wout = (const float*)d_in[5];
  const float* bout = (const float*)d_in[6];
  float* out = (float*)d_out;

  char* ws = (char*)d_ws;
  const size_t MB = (size_t)1 << 20;
  float* cosT          = (float*)(ws + 0 * MB);        // 2 MB
  float* sinT          = (float*)(ws + 2 * MB);        // 2 MB
  unsigned short* wqkb = (unsigned short*)(ws + 4 * MB);   // 1.5 MB (dead after gemm0)
  float* lpart         = (float*)(ws + 5 * MB + 512 * 1024); // 512 KB
  unsigned short* wob  = (unsigned short*)(ws + 6 * MB);   // 0.5 MB
  unsigned short* xn   = (unsigned short*)(ws + 8 * MB);   // 8 MB (dead after gemm0)
  float* opart         = (float*)(ws + 8 * MB);            // 32 MB (attn -> combine)
  unsigned short* qkv  = (unsigned short*)(ws + 16 * MB);  // 24 MB (dead after rope_split)
  unsigned short* qh   = (unsigned short*)(ws + 40 * MB);  // 8 MB (dead after attn)
  unsigned short* ao   = (unsigned short*)(ws + 40 * MB);  // 8 MB (combine -> gemm1)
  unsigned short* kh   = (unsigned short*)(ws + 48 * MB);  // 8 MB
  unsigned short* vt   = (unsigned short*)(ws + 56 * MB);  // 8 MB

  k_tables<<<(BATCH * NSEQ * 64) / 256, 256, 0, stream>>>(rot, cosT, sinT);
  k_cvt<<<(QKVN * DIM + 255) / 256, 256, 0, stream>>>(wqkv, wqkb, QKVN * DIM);
  k_cvt<<<(DIM * DIM + 255) / 256, 256, 0, stream>>>(wout, wob, DIM * DIM);
  k_ln<<<NROWS / 4, 256, 0, stream>>>(x, lnw, lnb, xn);
  k_gemm<0><<<dim3(NROWS / 128, QKVN / 128), 256, 0, stream>>>(xn, wqkb, qkv, nullptr,
                                                               NROWS, QKVN, DIM);
  k_rope_split<<<dim3(NSEQ / 128, 16), 256, 0, stream>>>(qkv, cosT, sinT, qh, kh, vt);
  k_attn<<<512, 256, 0, stream>>>(qh, kh, vt, opart, lpart);
  k_combine<<<dim3(NSEQ / 16, 16), 256, 0, stream>>>(opart, lpart, cosT, sinT, ao);
  k_gemm<1><<<dim3(NROWS / 128, DIM / 128), 256, 0, stream>>>(ao, wob, out, bout,
                                                              NROWS, DIM, DIM);
}

// Round 13
// 140.995 us; speedup vs baseline: 4.1246x; 1.0452x over previous
//
#include <hip/hip_runtime.h>
#include <cmath>

typedef short bf16x8 __attribute__((ext_vector_type(8)));
typedef float f32x2 __attribute__((ext_vector_type(2)));
typedef float f32x4 __attribute__((ext_vector_type(4)));
typedef float f32x16 __attribute__((ext_vector_type(16)));

#define NSEQ 4096
#define BATCH 2
#define DIM 512
#define HEADS 8
#define NROWS (BATCH * NSEQ)   // 8192
#define QKVN (3 * DIM)         // 1536

__device__ __forceinline__ unsigned short f2bf(float f) {
  unsigned int u = __float_as_uint(f);
  u += 0x7fffu + ((u >> 16) & 1u);
  return (unsigned short)(u >> 16);
}
__device__ __forceinline__ float bf2f(unsigned short h) {
  return __uint_as_float(((unsigned int)h) << 16);
}
__device__ __forceinline__ void gload16(const unsigned short* g, unsigned short* l) {
  __builtin_amdgcn_global_load_lds((const __attribute__((address_space(1))) unsigned int*)g,
                                   (__attribute__((address_space(3))) unsigned int*)l, 16, 0, 0);
}

// ---------------- fused prep: cos/sin tables + both weight converts ----------------
// blocks [0,2048): tables; [2048,5120): wqkv cvt; [5120,6144): wout cvt
__global__ __launch_bounds__(256) void k_prep(const float* __restrict__ rot,
                                              float* __restrict__ cosT,
                                              float* __restrict__ sinT,
                                              const float* __restrict__ wqkv,
                                              unsigned short* __restrict__ wqkb,
                                              const float* __restrict__ wout,
                                              unsigned short* __restrict__ wob) {
  int bid = blockIdx.x;
  int t = threadIdx.x;
  if (bid < 2048) {
    int i = bid * 256 + t;
    float f = rot[i];
    cosT[i] = cosf(f);
    sinT[i] = sinf(f);
  } else if (bid < 5120) {
    int i = (bid - 2048) * 256 + t;
    wqkb[i] = f2bf(wqkv[i]);
  } else {
    int i = (bid - 5120) * 256 + t;
    wob[i] = f2bf(wout[i]);
  }
}

// ---------------- LayerNorm: one wave per row ----------------
__global__ __launch_bounds__(256) void k_ln(const float* __restrict__ x,
                                            const float* __restrict__ w,
                                            const float* __restrict__ bb,
                                            unsigned short* __restrict__ xn) {
  int row = blockIdx.x * 4 + (threadIdx.x >> 6);
  int lane = threadIdx.x & 63;
  const float* xr = x + (size_t)row * DIM;
  float v[8];
  float s = 0.f;
#pragma unroll
  for (int j = 0; j < 8; ++j) { v[j] = xr[lane + j * 64]; s += v[j]; }
#pragma unroll
  for (int m = 1; m < 64; m <<= 1) s += __shfl_xor(s, m);
  float mu = s * (1.0f / DIM);
  float q = 0.f;
#pragma unroll
  for (int j = 0; j < 8; ++j) { float d = v[j] - mu; q += d * d; }
#pragma unroll
  for (int m = 1; m < 64; m <<= 1) q += __shfl_xor(q, m);
  float rs = rsqrtf(q * (1.0f / DIM) + 1e-5f);
#pragma unroll
  for (int j = 0; j < 8; ++j) {
    int col = lane + j * 64;
    xn[(size_t)row * DIM + col] = f2bf((v[j] - mu) * rs * w[col] + bb[col]);
  }
}

// ---------------- GEMM: C[M][N] = A[M][K] * B[N][K]^T (dbuf, 1 barrier/step) ----------------
template <int EPI>
__global__ __launch_bounds__(256) void k_gemm(const unsigned short* __restrict__ A,
                                              const unsigned short* __restrict__ B,
                                              void* __restrict__ C,
                                              const float* __restrict__ bias,
                                              int M, int N, int K) {
  __shared__ __align__(16) unsigned short As[2][128 * 32];
  __shared__ __align__(16) unsigned short Bs[2][128 * 32];
  int bm = blockIdx.x, bn = blockIdx.y;
  int tid = threadIdx.x;
  int lane = tid & 63, w = tid >> 6;
  int wm = (w >> 1) << 6, wn = (w & 1) << 6;
  f32x4 acc[4][4] = {};

#define GSTAGE(KT, BUF) do { \
  _Pragma("unroll") \
  for (int i = 0; i < 2; ++i) { \
    int c = tid + (i << 8); \
    int row = c >> 2, kc = (c & 3) << 3; \
    gload16(A + (size_t)(bm * 128 + row) * K + (KT) + kc, &As[BUF][(w * 64 + i * 256) * 8]); \
    gload16(B + (size_t)(bn * 128 + row) * K + (KT) + kc, &Bs[BUF][(w * 64 + i * 256) * 8]); \
  } } while (0)

  GSTAGE(0, 0);
  __syncthreads();
  int nk = K >> 5;
  for (int t = 0; t < nk; ++t) {
    int cur = t & 1;
    if (t + 1 < nk) GSTAGE((t + 1) << 5, cur ^ 1);
    bf16x8 af[4], bfr[4];
#pragma unroll
    for (int mi = 0; mi < 4; ++mi)
      af[mi] = *(const bf16x8*)&As[cur][(wm + mi * 16 + (lane & 15)) * 32 + ((lane >> 4) << 3)];
#pragma unroll
    for (int ni = 0; ni < 4; ++ni)
      bfr[ni] = *(const bf16x8*)&Bs[cur][(wn + ni * 16 + (lane & 15)) * 32 + ((lane >> 4) << 3)];
#pragma unroll
    for (int mi = 0; mi < 4; ++mi)
#pragma unroll
      for (int ni = 0; ni < 4; ++ni)
        acc[mi][ni] = __builtin_amdgcn_mfma_f32_16x16x32_bf16(af[mi], bfr[ni], acc[mi][ni], 0, 0, 0);
    __syncthreads();
  }
#undef GSTAGE
#pragma unroll
  for (int mi = 0; mi < 4; ++mi) {
#pragma unroll
    for (int ni = 0; ni < 4; ++ni) {
#pragma unroll
      for (int r = 0; r < 4; ++r) {
        int gm = bm * 128 + wm + mi * 16 + ((lane >> 4) << 2) + r;
        int gn = bn * 128 + wn + ni * 16 + (lane & 15);
        if (EPI == 0) {
          ((unsigned short*)C)[(size_t)gm * N + gn] = f2bf(acc[mi][ni][r]);
        } else {
          ((float*)C)[(size_t)gm * N + gn] = acc[mi][ni][r] + bias[gn];
        }
      }
    }
  }
}

// ------ RoPE + head split (+ V transpose); Q pre-scaled by 0.125*log2(e) (exp2-domain) ------
__global__ __launch_bounds__(256) void k_rope_split(const unsigned short* __restrict__ qkv,
                                                    const float* __restrict__ cosT,
                                                    const float* __restrict__ sinT,
                                                    unsigned short* __restrict__ qh,
                                                    unsigned short* __restrict__ kh,
                                                    unsigned short* __restrict__ vt) {
  __shared__ unsigned short vs[128][65];
  const float QSC = 0.125f * 1.44269504f;
  int nt = blockIdx.x, bh = blockIdx.y;
  int b = bh >> 3, h = bh & 7;
  int n0 = nt * 128;
  int t = threadIdx.x;
  int sub = t >> 3, cc = t & 7;
#pragma unroll
  for (int rr = 0; rr < 4; ++rr) {
    int row = rr * 32 + sub;
    int n = n0 + row;
    size_t base = ((size_t)(b * NSEQ + n)) * QKVN + h * 64 + cc * 8;
    const float* cb = cosT + ((size_t)(b * NSEQ + n)) * 64 + cc * 8;
    const float* sb = sinT + ((size_t)(b * NSEQ + n)) * 64 + cc * 8;
    float c[8], sn[8];
#pragma unroll
    for (int j = 0; j < 8; ++j) { c[j] = cb[j]; sn[j] = sb[j]; }
    bf16x8 qv = *(const bf16x8*)(qkv + base);
    bf16x8 kv = *(const bf16x8*)(qkv + base + 512);
    bf16x8 vv = *(const bf16x8*)(qkv + base + 1024);
    union { bf16x8 v; unsigned short u[8]; } yq, yk;
#pragma unroll
    for (int j = 0; j < 8; j += 2) {
      {
        float e = bf2f((unsigned short)qv[j]), o = bf2f((unsigned short)qv[j + 1]);
        yq.u[j]     = f2bf((e * c[j] - o * sn[j]) * QSC);
        yq.u[j + 1] = f2bf((o * c[j + 1] + e * sn[j + 1]) * QSC);
      }
      {
        float e = bf2f((unsigned short)kv[j]), o = bf2f((unsigned short)kv[j + 1]);
        yk.u[j]     = f2bf(e * c[j] - o * sn[j]);
        yk.u[j + 1] = f2bf(o * c[j + 1] + e * sn[j + 1]);
      }
      {
        float e = bf2f((unsigned short)vv[j]), o = bf2f((unsigned short)vv[j + 1]);
        vs[row][cc * 8 + j]     = f2bf(e * c[j] - o * sn[j]);
        vs[row][cc * 8 + j + 1] = f2bf(o * c[j + 1] + e * sn[j + 1]);
      }
    }
    *(bf16x8*)(qh + ((size_t)bh * NSEQ + n) * 64 + cc * 8) = yq.v;
    *(bf16x8*)(kh + ((size_t)bh * NSEQ + n) * 64 + cc * 8) = yk.v;
  }
  __syncthreads();
  int d = t >> 2, c4 = t & 3;
#pragma unroll
  for (int g = 0; g < 4; ++g) {
    union { bf16x8 v; unsigned short u[8]; } tv;
#pragma unroll
    for (int j = 0; j < 8; ++j) tv.u[j] = vs[c4 * 32 + g * 8 + j][d];
    *(bf16x8*)(vt + ((size_t)bh * 64 + d) * NSEQ + n0 + c4 * 32 + g * 8) = tv.v;
  }
}

// ---------------- Flash attention v13: v12 + anti-phase schedule + bf16 partials ----
// 512 blocks x 4 waves; block = (bh, 256-q tile, KV half); 64q/wave, 2 q-frags;
// 4-buffer LDS ring, depth-2 prefetch, counted vmcnt(8) + raw s_barrier per tile.
// NEW: waves 0,1 run phases (0,1); waves 2,3 run (1,0) -> at any instant half the
// block is in MFMA (QK^T/PV) and half in VALU (exp/pack) -> role-split overlap.
// Phases commute exactly (no-max exp2 softmax: acc,l are pure accumulations).
// NEW: partials stored bf16 (validated r10/r11, absmax unchanged).
__global__ __launch_bounds__(256, 2) void k_attn(const unsigned short* __restrict__ Qh,
                                                 const unsigned short* __restrict__ Kh,
                                                 const unsigned short* __restrict__ VT,
                                                 unsigned short* __restrict__ opart,
                                                 float* __restrict__ lpart) {
  __shared__ __align__(16) unsigned short Ks[4][64 * 64];
  __shared__ __align__(16) unsigned short Vs[4][64 * 64];
  int bid = blockIdx.x;
  int bh   = (bid & 7) + 8 * ((bid >> 7) & 1);  // XCD-pinned: bh%8 == bid%8
  int qt   = (bid >> 3) & 15;
  int half = (bid >> 8) & 1;
  int tid = threadIdx.x;
  int w = tid >> 6, lane = tid & 63;
  int lq = lane & 31, hi = lane >> 5;
  int q0 = qt * 256 + w * 64;
  int kv0 = half * 2048;
  int pswap = w >> 1;  // waves 2,3 reverse phase order

  const unsigned short* Kbh = Kh + (size_t)bh * NSEQ * 64;
  const unsigned short* Vbh = VT + (size_t)bh * 64 * NSEQ;

  const unsigned short* QbA = Qh + ((size_t)bh * NSEQ + q0 + lq) * 64 + hi * 8;
  const unsigned short* QbB = QbA + 32 * 64;
  bf16x8 qfA[4], qfB[4];
#pragma unroll
  for (int j = 0; j < 4; ++j) {
    qfA[j] = *(const bf16x8*)(QbA + j * 16);
    qfB[j] = *(const bf16x8*)(QbB + j * 16);
  }

  // staging chunk geometry: chunk c -> row r=c>>3, source 16B slot (c&7)^(r&7)
  int c0 = w * 64 + lane;
  int r0 = c0 >> 3, sw0 = ((c0 & 7) ^ (r0 & 7)) << 3;
  int c1 = c0 + 256;
  int r1 = c1 >> 3, sw1 = ((c1 & 7) ^ (r1 & 7)) << 3;
  int ld0 = (w * 64) * 8, ld1 = (256 + w * 64) * 8;

  f32x16 accA0 = (f32x16)0.0f, accA1 = (f32x16)0.0f;
  f32x16 accB0 = (f32x16)0.0f, accB1 = (f32x16)0.0f;
  float lA = 0.f, lB = 0.f;
  int swz = (lq & 7) << 4;

#define STAGE(T, BUF) do { \
  int tg_ = kv0 + (T) * 64; \
  gload16(Kbh + ((size_t)tg_ + r0) * 64 + sw0, &Ks[BUF][ld0]); \
  gload16(Kbh + ((size_t)tg_ + r1) * 64 + sw1, &Ks[BUF][ld1]); \
  gload16(Vbh + (size_t)r0 * NSEQ + tg_ + sw0, &Vs[BUF][ld0]); \
  gload16(Vbh + (size_t)r1 * NSEQ + tg_ + sw1, &Vs[BUF][ld1]); \
} while (0)

  // prologue: prefetch tiles 0 and 1 (8 loads in flight)
  STAGE(0, 0);
  STAGE(1, 1);

  for (int t = 0; t < 32; ++t) {
    int rd = t & 3;
    if (t < 30) {
      STAGE(t + 2, (t + 2) & 3);
      asm volatile("s_waitcnt vmcnt(8)" ::: "memory");
    } else if (t == 30) {
      asm volatile("s_waitcnt vmcnt(4)" ::: "memory");
    } else {
      asm volatile("s_waitcnt vmcnt(0)" ::: "memory");
    }
    __builtin_amdgcn_s_barrier();
    asm volatile("" ::: "memory");
    const char* kb_ = (const char*)&Ks[rd][0];
    const char* vb_ = (const char*)&Vs[rd][0];
#pragma unroll
    for (int pp = 0; pp < 2; ++pp) {
      int ph = pp ^ pswap;  // anti-phase across wave halves
      // ---- QK^T: 32 k-rows x 64 q (each a-read feeds both q-frags) ----
      f32x16 sA = (f32x16)0.0f, sB = (f32x16)0.0f;
      __builtin_amdgcn_s_setprio(1);
#pragma unroll
      for (int j = 0; j < 4; ++j) {
        int cb = j * 32 + hi * 16;
        bf16x8 a = *(const bf16x8*)(kb_ + (ph * 32 + lq) * 128 + (cb ^ swz));
        sA = __builtin_amdgcn_mfma_f32_32x32x16_bf16(a, qfA[j], sA, 0, 0, 0);
        sB = __builtin_amdgcn_mfma_f32_32x32x16_bf16(a, qfB[j], sB, 0, 0, 0);
      }
      __builtin_amdgcn_s_setprio(0);
      // ---- exp2 (raw) + packed sums ----
#pragma unroll
      for (int r = 0; r < 16; ++r) sA[r] = __builtin_amdgcn_exp2f(sA[r]);
#pragma unroll
      for (int r = 0; r < 16; ++r) sB[r] = __builtin_amdgcn_exp2f(sB[r]);
      {
        union { f32x16 v; f32x2 p[8]; } ua, ub; ua.v = sA; ub.v = sB;
        f32x2 a01 = ua.p[0] + ua.p[1], a23 = ua.p[2] + ua.p[3];
        f32x2 a45 = ua.p[4] + ua.p[5], a67 = ua.p[6] + ua.p[7];
        f32x2 ta = (a01 + a23) + (a45 + a67);
        lA += ta.x + ta.y;
        f32x2 b01 = ub.p[0] + ub.p[1], b23 = ub.p[2] + ub.p[3];
        f32x2 b45 = ub.p[4] + ub.p[5], b67 = ub.p[6] + ub.p[7];
        f32x2 tb = (b01 + b23) + (b45 + b67);
        lB += tb.x + tb.y;
      }
      // ---- pack P -> bf16 ----
      unsigned int dwA[8], dwB[8];
#pragma unroll
      for (int m = 0; m < 8; ++m) {
        asm("v_cvt_pk_bf16_f32 %0, %1, %2" : "=v"(dwA[m]) : "v"(sA[2 * m]), "v"(sA[2 * m + 1]));
        asm("v_cvt_pk_bf16_f32 %0, %1, %2" : "=v"(dwB[m]) : "v"(sB[2 * m]), "v"(sB[2 * m + 1]));
      }
      // ---- PV: each v-read feeds both q-frags; exchange via shfl_xor (proven) ----
      __builtin_amdgcn_s_setprio(1);
#pragma unroll
      for (int kk = 0; kk < 2; ++kk) {
        const int B = 4 * kk;
        unsigned int svA0 = hi ? dwA[B + 0] : dwA[B + 2];
        unsigned int svA1 = hi ? dwA[B + 1] : dwA[B + 3];
        unsigned int svB0 = hi ? dwB[B + 0] : dwB[B + 2];
        unsigned int svB1 = hi ? dwB[B + 1] : dwB[B + 3];
        unsigned int rvA0 = (unsigned int)__shfl_xor((int)svA0, 32);
        unsigned int rvA1 = (unsigned int)__shfl_xor((int)svA1, 32);
        unsigned int rvB0 = (unsigned int)__shfl_xor((int)svB0, 32);
        unsigned int rvB1 = (unsigned int)__shfl_xor((int)svB1, 32);
        union { unsigned int d[4]; bf16x8 v; } puA, puB;
        puA.d[0] = hi ? rvA0 : dwA[B + 0];
        puA.d[1] = hi ? rvA1 : dwA[B + 1];
        puA.d[2] = hi ? dwA[B + 2] : rvA0;
        puA.d[3] = hi ? dwA[B + 3] : rvA1;
        puB.d[0] = hi ? rvB0 : dwB[B + 0];
        puB.d[1] = hi ? rvB1 : dwB[B + 1];
        puB.d[2] = hi ? dwB[B + 2] : rvB0;
        puB.d[3] = hi ? dwB[B + 3] : rvB1;
        int cb = (ph * 2 + kk) * 32 + hi * 16;
        bf16x8 v0 = *(const bf16x8*)(vb_ + lq * 128 + (cb ^ swz));
        bf16x8 v1 = *(const bf16x8*)(vb_ + (32 + lq) * 128 + (cb ^ swz));
        accA0 = __builtin_amdgcn_mfma_f32_32x32x16_bf16(v0, puA.v, accA0, 0, 0, 0);
        accA1 = __builtin_amdgcn_mfma_f32_32x32x16_bf16(v1, puA.v, accA1, 0, 0, 0);
        accB0 = __builtin_amdgcn_mfma_f32_32x32x16_bf16(v0, puB.v, accB0, 0, 0, 0);
        accB1 = __builtin_amdgcn_mfma_f32_32x32x16_bf16(v1, puB.v, accB1, 0, 0, 0);
      }
      __builtin_amdgcn_s_setprio(0);
    }
  }
#undef STAGE

  // ---- epilogue: write bf16 partials for both q-frags ----
  float lsumA = lA + __shfl_xor(lA, 32);
  float lsumB = lB + __shfl_xor(lB, 32);
  size_t qrowA = (size_t)(half * 16 + bh) * NSEQ + q0 + lq;
  size_t qrowB = qrowA + 32;
  if (hi == 0) {
    lpart[qrowA] = lsumA;
    lpart[qrowB] = lsumB;
  }
  unsigned short* obA = opart + qrowA * 64;
  unsigned short* obB = opart + qrowB * 64;
#pragma unroll
  for (int rg = 0; rg < 4; ++rg) {
    unsigned int pa0[2], pa1[2], pb0[2], pb1[2];
    asm("v_cvt_pk_bf16_f32 %0, %1, %2" : "=v"(pa0[0]) : "v"(accA0[4 * rg + 0]), "v"(accA0[4 * rg + 1]));
    asm("v_cvt_pk_bf16_f32 %0, %1, %2" : "=v"(pa0[1]) : "v"(accA0[4 * rg + 2]), "v"(accA0[4 * rg + 3]));
    asm("v_cvt_pk_bf16_f32 %0, %1, %2" : "=v"(pa1[0]) : "v"(accA1[4 * rg + 0]), "v"(accA1[4 * rg + 1]));
    asm("v_cvt_pk_bf16_f32 %0, %1, %2" : "=v"(pa1[1]) : "v"(accA1[4 * rg + 2]), "v"(accA1[4 * rg + 3]));
    asm("v_cvt_pk_bf16_f32 %0, %1, %2" : "=v"(pb0[0]) : "v"(accB0[4 * rg + 0]), "v"(accB0[4 * rg + 1]));
    asm("v_cvt_pk_bf16_f32 %0, %1, %2" : "=v"(pb0[1]) : "v"(accB0[4 * rg + 2]), "v"(accB0[4 * rg + 3]));
    asm("v_cvt_pk_bf16_f32 %0, %1, %2" : "=v"(pb1[0]) : "v"(accB1[4 * rg + 0]), "v"(accB1[4 * rg + 1]));
    asm("v_cvt_pk_bf16_f32 %0, %1, %2" : "=v"(pb1[1]) : "v"(accB1[4 * rg + 2]), "v"(accB1[4 * rg + 3]));
    *(uint2*)(obA + 8 * rg + 4 * hi) = *(uint2*)pa0;
    *(uint2*)(obA + 32 + 8 * rg + 4 * hi) = *(uint2*)pa1;
    *(uint2*)(obB + 8 * rg + 4 * hi) = *(uint2*)pb0;
    *(uint2*)(obB + 32 + 8 * rg + 4 * hi) = *(uint2*)pb1;
  }
}

// ---------------- combine 2 halves (bf16) + normalize + inverse RoPE -> ao ----------------
__global__ __launch_bounds__(256) void k_combine(const unsigned short* __restrict__ opart,
                                                 const float* __restrict__ lpart,
                                                 const float* __restrict__ cosT,
                                                 const float* __restrict__ sinT,
                                                 unsigned short* __restrict__ ao) {
  int bh = blockIdx.y;
  int b = bh >> 3, h = bh & 7;
  int t = threadIdx.x;
  int q = blockIdx.x * 16 + (t >> 4);
  int d = (t & 15) * 4;
  size_t i0 = (size_t)bh * NSEQ + q;
  const size_t HOFF = (size_t)16 * NSEQ;
  float l = lpart[i0] + lpart[i0 + HOFF];
  float o[4] = {0.f, 0.f, 0.f, 0.f};
#pragma unroll
  for (int p = 0; p < 2; ++p) {
    uint2 u = *(const uint2*)(opart + (i0 + p * HOFF) * 64 + d);
    o[0] += bf2f((unsigned short)(u.x & 0xffff));
    o[1] += bf2f((unsigned short)(u.x >> 16));
    o[2] += bf2f((unsigned short)(u.y & 0xffff));
    o[3] += bf2f((unsigned short)(u.y >> 16));
  }
  float inv = 1.0f / l;
  float4 c4 = *(const float4*)(cosT + ((size_t)b * NSEQ + q) * 64 + d);
  float4 s4 = *(const float4*)(sinT + ((size_t)b * NSEQ + q) * 64 + d);
  float yx = o[0] * inv;
  float yy = o[1] * inv;
  float yz = o[2] * inv;
  float yw = o[3] * inv;
  float r0 = yx * c4.x + yy * s4.x;
  float r1 = yy * c4.y - yx * s4.y;
  float r2 = yz * c4.z + yw * s4.z;
  float r3 = yw * c4.w - yz * s4.w;
  unsigned int w0, w1;
  asm("v_cvt_pk_bf16_f32 %0, %1, %2" : "=v"(w0) : "v"(r0), "v"(r1));
  asm("v_cvt_pk_bf16_f32 %0, %1, %2" : "=v"(w1) : "v"(r2), "v"(r3));
  unsigned int uu[2] = {w0, w1};
  *(uint2*)(ao + ((size_t)b * NSEQ + q) * DIM + h * 64 + d) = *(uint2*)uu;
}

extern "C" void kernel_launch(void* const* d_in, const int* in_sizes, int n_in,
                              void* d_out, int out_size, void* d_ws, size_t ws_size,
                              hipStream_t stream) {
  const float* x    = (const float*)d_in[0];
  const float* rot  = (const float*)d_in[1];
  const float* lnw  = (const float*)d_in[2];
  const float* lnb  = (const float*)d_in[3];
  const float* wqkv = (const float*)d_in[4];
  const float* wout = (const float*)d_in[5];
  const float* bout = (const float*)d_in[6];
  float* out = (float*)d_out;

  char* ws = (char*)d_ws;
  const size_t MB = (size_t)1 << 20;
  float* cosT          = (float*)(ws + 0 * MB);        // 2 MB
  float* sinT          = (float*)(ws + 2 * MB);        // 2 MB
  unsigned short* wqkb = (unsigned short*)(ws + 4 * MB);   // 1.5 MB (dead after gemm0)
  float* lpart         = (float*)(ws + 5 * MB + 512 * 1024); // 512 KB
  unsigned short* wob  = (unsigned short*)(ws + 6 * MB);   // 0.5 MB
  unsigned short* xn   = (unsigned short*)(ws + 8 * MB);   // 8 MB (dead after gemm0)
  unsigned short* opart = (unsigned short*)(ws + 8 * MB);  // 16 MB bf16 (8-24, attn -> combine)
  unsigned short* qkv  = (unsigned short*)(ws + 16 * MB);  // 24 MB (dead after rope_split)
  unsigned short* qh   = (unsigned short*)(ws + 40 * MB);  // 8 MB (dead after attn)
  unsigned short* ao   = (unsigned short*)(ws + 40 * MB);  // 8 MB (combine -> gemm1)
  unsigned short* kh   = (unsigned short*)(ws + 48 * MB);  // 8 MB
  unsigned short* vt   = (unsigned short*)(ws + 56 * MB);  // 8 MB

  k_prep<<<6144, 256, 0, stream>>>(rot, cosT, sinT, wqkv, wqkb, wout, wob);
  k_ln<<<NROWS / 4, 256, 0, stream>>>(x, lnw, lnb, xn);
  k_gemm<0><<<dim3(NROWS / 128, QKVN / 128), 256, 0, stream>>>(xn, wqkb, qkv, nullptr,
                                                               NROWS, QKVN, DIM);
  k_rope_split<<<dim3(NSEQ / 128, 16), 256, 0, stream>>>(qkv, cosT, sinT, qh, kh, vt);
  k_attn<<<512, 256, 0, stream>>>(qh, kh, vt, opart, lpart);
  k_combine<<<dim3(NSEQ / 16, 16), 256, 0, stream>>>(opart, lpart, cosT, sinT, ao);
  k_gemm<1><<<dim3(NROWS / 128, DIM / 128), 256, 0, stream>>>(ao, wob, out, bout,
                                                              NROWS, DIM, DIM);
}

// Round 14
// 136.019 us; speedup vs baseline: 4.2755x; 1.0366x over previous
//
#include <hip/hip_runtime.h>
#include <cmath>

typedef short bf16x8 __attribute__((ext_vector_type(8)));
typedef float f32x2 __attribute__((ext_vector_type(2)));
typedef float f32x4 __attribute__((ext_vector_type(4)));
typedef float f32x16 __attribute__((ext_vector_type(16)));

#define NSEQ 4096
#define BATCH 2
#define DIM 512
#define HEADS 8
#define NROWS (BATCH * NSEQ)   // 8192
#define QKVN (3 * DIM)         // 1536

__device__ __forceinline__ unsigned short f2bf(float f) {
  unsigned int u = __float_as_uint(f);
  u += 0x7fffu + ((u >> 16) & 1u);
  return (unsigned short)(u >> 16);
}
__device__ __forceinline__ float bf2f(unsigned short h) {
  return __uint_as_float(((unsigned int)h) << 16);
}
__device__ __forceinline__ void gload16(const unsigned short* g, unsigned short* l) {
  __builtin_amdgcn_global_load_lds((const __attribute__((address_space(1))) unsigned int*)g,
                                   (__attribute__((address_space(3))) unsigned int*)l, 16, 0, 0);
}

// ---------------- fused prep: trig tables (HW sin/cos) + weight cvts + LayerNorm ----------------
// blocks [0,2048): tables; [2048,5120): wqkv cvt; [5120,6144): wout cvt; [6144,8192): LN
__global__ __launch_bounds__(256) void k_prep(const float* __restrict__ rot,
                                              float* __restrict__ cosT,
                                              float* __restrict__ sinT,
                                              const float* __restrict__ wqkv,
                                              unsigned short* __restrict__ wqkb,
                                              const float* __restrict__ wout,
                                              unsigned short* __restrict__ wob,
                                              const float* __restrict__ x,
                                              const float* __restrict__ lnw,
                                              const float* __restrict__ lnb,
                                              unsigned short* __restrict__ xn) {
  const float INV2PI = 0.15915494309f;
  int bid = blockIdx.x;
  int t = threadIdx.x;
  if (bid < 2048) {
    int i = bid * 256 + t;
    float rv = rot[i] * INV2PI;           // v_sin/v_cos take revolutions
    cosT[i] = __builtin_amdgcn_cosf(rv);
    sinT[i] = __builtin_amdgcn_sinf(rv);
  } else if (bid < 5120) {
    int i = (bid - 2048) * 256 + t;
    wqkb[i] = f2bf(wqkv[i]);
  } else if (bid < 6144) {
    int i = (bid - 5120) * 256 + t;
    wob[i] = f2bf(wout[i]);
  } else {
    int row = (bid - 6144) * 4 + (t >> 6);
    int lane = t & 63;
    const float* xr = x + (size_t)row * DIM;
    float v[8];
    float s = 0.f;
#pragma unroll
    for (int j = 0; j < 8; ++j) { v[j] = xr[lane + j * 64]; s += v[j]; }
#pragma unroll
    for (int m = 1; m < 64; m <<= 1) s += __shfl_xor(s, m);
    float mu = s * (1.0f / DIM);
    float q = 0.f;
#pragma unroll
    for (int j = 0; j < 8; ++j) { float d = v[j] - mu; q += d * d; }
#pragma unroll
    for (int m = 1; m < 64; m <<= 1) q += __shfl_xor(q, m);
    float rs = rsqrtf(q * (1.0f / DIM) + 1e-5f);
#pragma unroll
    for (int j = 0; j < 8; ++j) {
      int col = lane + j * 64;
      xn[(size_t)row * DIM + col] = f2bf((v[j] - mu) * rs * lnw[col] + lnb[col]);
    }
  }
}

// ---------------- GEMM: C[M][N] = A[M*(TM/128 scale)][K] * B[N][K]^T (dbuf, 1 barrier/step) ----
// TM = block M-tile (128 or 64); N-tile fixed 128. 4 waves: wave tile (TM/2) x 64.
template <int EPI, int TM>
__global__ __launch_bounds__(256) void k_gemm(const unsigned short* __restrict__ A,
                                              const unsigned short* __restrict__ B,
                                              void* __restrict__ C,
                                              const float* __restrict__ bias,
                                              int M, int N, int K) {
  constexpr int MI = TM / 32;  // acc rows per wave (4 or 2)
  __shared__ __align__(16) unsigned short As[2][TM * 32];
  __shared__ __align__(16) unsigned short Bs[2][128 * 32];
  int bm = blockIdx.x, bn = blockIdx.y;
  int tid = threadIdx.x;
  int lane = tid & 63, w = tid >> 6;
  int wm = (w >> 1) * (TM / 2), wn = (w & 1) << 6;
  f32x4 acc[MI][4] = {};

#define GSTAGE(KT, BUF) do { \
  if constexpr (TM == 128) { \
    _Pragma("unroll") \
    for (int i = 0; i < 2; ++i) { \
      int c = tid + (i << 8); \
      int row = c >> 2, kc = (c & 3) << 3; \
      gload16(A + (size_t)(bm * 128 + row) * K + (KT) + kc, &As[BUF][(w * 64 + i * 256) * 8]); \
    } \
  } else { \
    int row = tid >> 2, kc = (tid & 3) << 3; \
    gload16(A + (size_t)(bm * 64 + row) * K + (KT) + kc, &As[BUF][(w * 64) * 8]); \
  } \
  _Pragma("unroll") \
  for (int i = 0; i < 2; ++i) { \
    int c = tid + (i << 8); \
    int row = c >> 2, kc = (c & 3) << 3; \
    gload16(B + (size_t)(bn * 128 + row) * K + (KT) + kc, &Bs[BUF][(w * 64 + i * 256) * 8]); \
  } } while (0)

  GSTAGE(0, 0);
  __syncthreads();
  int nk = K >> 5;
  for (int t = 0; t < nk; ++t) {
    int cur = t & 1;
    if (t + 1 < nk) GSTAGE((t + 1) << 5, cur ^ 1);
    bf16x8 af[MI], bfr[4];
#pragma unroll
    for (int mi = 0; mi < MI; ++mi)
      af[mi] = *(const bf16x8*)&As[cur][(wm + mi * 16 + (lane & 15)) * 32 + ((lane >> 4) << 3)];
#pragma unroll
    for (int ni = 0; ni < 4; ++ni)
      bfr[ni] = *(const bf16x8*)&Bs[cur][(wn + ni * 16 + (lane & 15)) * 32 + ((lane >> 4) << 3)];
#pragma unroll
    for (int mi = 0; mi < MI; ++mi)
#pragma unroll
      for (int ni = 0; ni < 4; ++ni)
        acc[mi][ni] = __builtin_amdgcn_mfma_f32_16x16x32_bf16(af[mi], bfr[ni], acc[mi][ni], 0, 0, 0);
    __syncthreads();
  }
#undef GSTAGE
#pragma unroll
  for (int mi = 0; mi < MI; ++mi) {
#pragma unroll
    for (int ni = 0; ni < 4; ++ni) {
#pragma unroll
      for (int r = 0; r < 4; ++r) {
        int gm = bm * TM + wm + mi * 16 + ((lane >> 4) << 2) + r;
        int gn = bn * 128 + wn + ni * 16 + (lane & 15);
        if (EPI == 0) {
          ((unsigned short*)C)[(size_t)gm * N + gn] = f2bf(acc[mi][ni][r]);
        } else {
          ((float*)C)[(size_t)gm * N + gn] = acc[mi][ni][r] + bias[gn];
        }
      }
    }
  }
}

// ------ RoPE + head split (+ V transpose); Q pre-scaled by 0.125*log2(e) (exp2-domain) ------
__global__ __launch_bounds__(256) void k_rope_split(const unsigned short* __restrict__ qkv,
                                                    const float* __restrict__ cosT,
                                                    const float* __restrict__ sinT,
                                                    unsigned short* __restrict__ qh,
                                                    unsigned short* __restrict__ kh,
                                                    unsigned short* __restrict__ vt) {
  __shared__ unsigned short vs[128][65];
  const float QSC = 0.125f * 1.44269504f;
  int nt = blockIdx.x, bh = blockIdx.y;
  int b = bh >> 3, h = bh & 7;
  int n0 = nt * 128;
  int t = threadIdx.x;
  int sub = t >> 3, cc = t & 7;
#pragma unroll
  for (int rr = 0; rr < 4; ++rr) {
    int row = rr * 32 + sub;
    int n = n0 + row;
    size_t base = ((size_t)(b * NSEQ + n)) * QKVN + h * 64 + cc * 8;
    const float* cb = cosT + ((size_t)(b * NSEQ + n)) * 64 + cc * 8;
    const float* sb = sinT + ((size_t)(b * NSEQ + n)) * 64 + cc * 8;
    float c[8], sn[8];
#pragma unroll
    for (int j = 0; j < 8; ++j) { c[j] = cb[j]; sn[j] = sb[j]; }
    bf16x8 qv = *(const bf16x8*)(qkv + base);
    bf16x8 kv = *(const bf16x8*)(qkv + base + 512);
    bf16x8 vv = *(const bf16x8*)(qkv + base + 1024);
    union { bf16x8 v; unsigned short u[8]; } yq, yk;
#pragma unroll
    for (int j = 0; j < 8; j += 2) {
      {
        float e = bf2f((unsigned short)qv[j]), o = bf2f((unsigned short)qv[j + 1]);
        yq.u[j]     = f2bf((e * c[j] - o * sn[j]) * QSC);
        yq.u[j + 1] = f2bf((o * c[j + 1] + e * sn[j + 1]) * QSC);
      }
      {
        float e = bf2f((unsigned short)kv[j]), o = bf2f((unsigned short)kv[j + 1]);
        yk.u[j]     = f2bf(e * c[j] - o * sn[j]);
        yk.u[j + 1] = f2bf(o * c[j + 1] + e * sn[j + 1]);
      }
      {
        float e = bf2f((unsigned short)vv[j]), o = bf2f((unsigned short)vv[j + 1]);
        vs[row][cc * 8 + j]     = f2bf(e * c[j] - o * sn[j]);
        vs[row][cc * 8 + j + 1] = f2bf(o * c[j + 1] + e * sn[j + 1]);
      }
    }
    *(bf16x8*)(qh + ((size_t)bh * NSEQ + n) * 64 + cc * 8) = yq.v;
    *(bf16x8*)(kh + ((size_t)bh * NSEQ + n) * 64 + cc * 8) = yk.v;
  }
  __syncthreads();
  int d = t >> 2, c4 = t & 3;
#pragma unroll
  for (int g = 0; g < 4; ++g) {
    union { bf16x8 v; unsigned short u[8]; } tv;
#pragma unroll
    for (int j = 0; j < 8; ++j) tv.u[j] = vs[c4 * 32 + g * 8 + j][d];
    *(bf16x8*)(vt + ((size_t)bh * 64 + d) * NSEQ + n0 + c4 * 32 + g * 8) = tv.v;
  }
}

// ---------------- Flash attention v14 (= v12 core, bf16 partials): KV-split-2, 64q/wave ----
// 512 blocks x 4 waves; 4-buffer LDS ring, depth-2 prefetch, counted vmcnt(8) + raw
// s_barrier per tile (never drain in steady state). shfl_xor exchange (proven).
__global__ __launch_bounds__(256, 2) void k_attn(const unsigned short* __restrict__ Qh,
                                                 const unsigned short* __restrict__ Kh,
                                                 const unsigned short* __restrict__ VT,
                                                 unsigned short* __restrict__ opart,
                                                 float* __restrict__ lpart) {
  __shared__ __align__(16) unsigned short Ks[4][64 * 64];
  __shared__ __align__(16) unsigned short Vs[4][64 * 64];
  int bid = blockIdx.x;
  int bh   = (bid & 7) + 8 * ((bid >> 7) & 1);  // XCD-pinned: bh%8 == bid%8
  int qt   = (bid >> 3) & 15;
  int half = (bid >> 8) & 1;
  int tid = threadIdx.x;
  int w = tid >> 6, lane = tid & 63;
  int lq = lane & 31, hi = lane >> 5;
  int q0 = qt * 256 + w * 64;
  int kv0 = half * 2048;

  const unsigned short* Kbh = Kh + (size_t)bh * NSEQ * 64;
  const unsigned short* Vbh = VT + (size_t)bh * 64 * NSEQ;

  const unsigned short* QbA = Qh + ((size_t)bh * NSEQ + q0 + lq) * 64 + hi * 8;
  const unsigned short* QbB = QbA + 32 * 64;
  bf16x8 qfA[4], qfB[4];
#pragma unroll
  for (int j = 0; j < 4; ++j) {
    qfA[j] = *(const bf16x8*)(QbA + j * 16);
    qfB[j] = *(const bf16x8*)(QbB + j * 16);
  }

  // staging chunk geometry: chunk c -> row r=c>>3, source 16B slot (c&7)^(r&7)
  int c0 = w * 64 + lane;
  int r0 = c0 >> 3, sw0 = ((c0 & 7) ^ (r0 & 7)) << 3;
  int c1 = c0 + 256;
  int r1 = c1 >> 3, sw1 = ((c1 & 7) ^ (r1 & 7)) << 3;
  int ld0 = (w * 64) * 8, ld1 = (256 + w * 64) * 8;

  f32x16 accA0 = (f32x16)0.0f, accA1 = (f32x16)0.0f;
  f32x16 accB0 = (f32x16)0.0f, accB1 = (f32x16)0.0f;
  float lA = 0.f, lB = 0.f;
  int swz = (lq & 7) << 4;

#define STAGE(T, BUF) do { \
  int tg_ = kv0 + (T) * 64; \
  gload16(Kbh + ((size_t)tg_ + r0) * 64 + sw0, &Ks[BUF][ld0]); \
  gload16(Kbh + ((size_t)tg_ + r1) * 64 + sw1, &Ks[BUF][ld1]); \
  gload16(Vbh + (size_t)r0 * NSEQ + tg_ + sw0, &Vs[BUF][ld0]); \
  gload16(Vbh + (size_t)r1 * NSEQ + tg_ + sw1, &Vs[BUF][ld1]); \
} while (0)

  // prologue: prefetch tiles 0 and 1 (8 loads in flight)
  STAGE(0, 0);
  STAGE(1, 1);

  for (int t = 0; t < 32; ++t) {
    int rd = t & 3;
    if (t < 30) {
      STAGE(t + 2, (t + 2) & 3);
      asm volatile("s_waitcnt vmcnt(8)" ::: "memory");
    } else if (t == 30) {
      asm volatile("s_waitcnt vmcnt(4)" ::: "memory");
    } else {
      asm volatile("s_waitcnt vmcnt(0)" ::: "memory");
    }
    __builtin_amdgcn_s_barrier();
    asm volatile("" ::: "memory");
    const char* kb_ = (const char*)&Ks[rd][0];
    const char* vb_ = (const char*)&Vs[rd][0];
#pragma unroll
    for (int ph = 0; ph < 2; ++ph) {
      // ---- QK^T: 32 k-rows x 64 q (each a-read feeds both q-frags) ----
      f32x16 sA = (f32x16)0.0f, sB = (f32x16)0.0f;
      __builtin_amdgcn_s_setprio(1);
#pragma unroll
      for (int j = 0; j < 4; ++j) {
        int cb = j * 32 + hi * 16;
        bf16x8 a = *(const bf16x8*)(kb_ + (ph * 32 + lq) * 128 + (cb ^ swz));
        sA = __builtin_amdgcn_mfma_f32_32x32x16_bf16(a, qfA[j], sA, 0, 0, 0);
        sB = __builtin_amdgcn_mfma_f32_32x32x16_bf16(a, qfB[j], sB, 0, 0, 0);
      }
      __builtin_amdgcn_s_setprio(0);
      // ---- exp2 (raw) + packed sums ----
#pragma unroll
      for (int r = 0; r < 16; ++r) sA[r] = __builtin_amdgcn_exp2f(sA[r]);
#pragma unroll
      for (int r = 0; r < 16; ++r) sB[r] = __builtin_amdgcn_exp2f(sB[r]);
      {
        union { f32x16 v; f32x2 p[8]; } ua, ub; ua.v = sA; ub.v = sB;
        f32x2 a01 = ua.p[0] + ua.p[1], a23 = ua.p[2] + ua.p[3];
        f32x2 a45 = ua.p[4] + ua.p[5], a67 = ua.p[6] + ua.p[7];
        f32x2 ta = (a01 + a23) + (a45 + a67);
        lA += ta.x + ta.y;
        f32x2 b01 = ub.p[0] + ub.p[1], b23 = ub.p[2] + ub.p[3];
        f32x2 b45 = ub.p[4] + ub.p[5], b67 = ub.p[6] + ub.p[7];
        f32x2 tb = (b01 + b23) + (b45 + b67);
        lB += tb.x + tb.y;
      }
      // ---- pack P -> bf16 ----
      unsigned int dwA[8], dwB[8];
#pragma unroll
      for (int m = 0; m < 8; ++m) {
        asm("v_cvt_pk_bf16_f32 %0, %1, %2" : "=v"(dwA[m]) : "v"(sA[2 * m]), "v"(sA[2 * m + 1]));
        asm("v_cvt_pk_bf16_f32 %0, %1, %2" : "=v"(dwB[m]) : "v"(sB[2 * m]), "v"(sB[2 * m + 1]));
      }
      // ---- PV: each v-read feeds both q-frags; exchange via shfl_xor (proven) ----
      __builtin_amdgcn_s_setprio(1);
#pragma unroll
      for (int kk = 0; kk < 2; ++kk) {
        const int B = 4 * kk;
        unsigned int svA0 = hi ? dwA[B + 0] : dwA[B + 2];
        unsigned int svA1 = hi ? dwA[B + 1] : dwA[B + 3];
        unsigned int svB0 = hi ? dwB[B + 0] : dwB[B + 2];
        unsigned int svB1 = hi ? dwB[B + 1] : dwB[B + 3];
        unsigned int rvA0 = (unsigned int)__shfl_xor((int)svA0, 32);
        unsigned int rvA1 = (unsigned int)__shfl_xor((int)svA1, 32);
        unsigned int rvB0 = (unsigned int)__shfl_xor((int)svB0, 32);
        unsigned int rvB1 = (unsigned int)__shfl_xor((int)svB1, 32);
        union { unsigned int d[4]; bf16x8 v; } puA, puB;
        puA.d[0] = hi ? rvA0 : dwA[B + 0];
        puA.d[1] = hi ? rvA1 : dwA[B + 1];
        puA.d[2] = hi ? dwA[B + 2] : rvA0;
        puA.d[3] = hi ? dwA[B + 3] : rvA1;
        puB.d[0] = hi ? rvB0 : dwB[B + 0];
        puB.d[1] = hi ? rvB1 : dwB[B + 1];
        puB.d[2] = hi ? dwB[B + 2] : rvB0;
        puB.d[3] = hi ? dwB[B + 3] : rvB1;
        int cb = (ph * 2 + kk) * 32 + hi * 16;
        bf16x8 v0 = *(const bf16x8*)(vb_ + lq * 128 + (cb ^ swz));
        bf16x8 v1 = *(const bf16x8*)(vb_ + (32 + lq) * 128 + (cb ^ swz));
        accA0 = __builtin_amdgcn_mfma_f32_32x32x16_bf16(v0, puA.v, accA0, 0, 0, 0);
        accA1 = __builtin_amdgcn_mfma_f32_32x32x16_bf16(v1, puA.v, accA1, 0, 0, 0);
        accB0 = __builtin_amdgcn_mfma_f32_32x32x16_bf16(v0, puB.v, accB0, 0, 0, 0);
        accB1 = __builtin_amdgcn_mfma_f32_32x32x16_bf16(v1, puB.v, accB1, 0, 0, 0);
      }
      __builtin_amdgcn_s_setprio(0);
    }
  }
#undef STAGE

  // ---- epilogue: write bf16 partials for both q-frags ----
  float lsumA = lA + __shfl_xor(lA, 32);
  float lsumB = lB + __shfl_xor(lB, 32);
  size_t qrowA = (size_t)(half * 16 + bh) * NSEQ + q0 + lq;
  size_t qrowB = qrowA + 32;
  if (hi == 0) {
    lpart[qrowA] = lsumA;
    lpart[qrowB] = lsumB;
  }
  unsigned short* obA = opart + qrowA * 64;
  unsigned short* obB = opart + qrowB * 64;
#pragma unroll
  for (int rg = 0; rg < 4; ++rg) {
    unsigned int pa0[2], pa1[2], pb0[2], pb1[2];
    asm("v_cvt_pk_bf16_f32 %0, %1, %2" : "=v"(pa0[0]) : "v"(accA0[4 * rg + 0]), "v"(accA0[4 * rg + 1]));
    asm("v_cvt_pk_bf16_f32 %0, %1, %2" : "=v"(pa0[1]) : "v"(accA0[4 * rg + 2]), "v"(accA0[4 * rg + 3]));
    asm("v_cvt_pk_bf16_f32 %0, %1, %2" : "=v"(pa1[0]) : "v"(accA1[4 * rg + 0]), "v"(accA1[4 * rg + 1]));
    asm("v_cvt_pk_bf16_f32 %0, %1, %2" : "=v"(pa1[1]) : "v"(accA1[4 * rg + 2]), "v"(accA1[4 * rg + 3]));
    asm("v_cvt_pk_bf16_f32 %0, %1, %2" : "=v"(pb0[0]) : "v"(accB0[4 * rg + 0]), "v"(accB0[4 * rg + 1]));
    asm("v_cvt_pk_bf16_f32 %0, %1, %2" : "=v"(pb0[1]) : "v"(accB0[4 * rg + 2]), "v"(accB0[4 * rg + 3]));
    asm("v_cvt_pk_bf16_f32 %0, %1, %2" : "=v"(pb1[0]) : "v"(accB1[4 * rg + 0]), "v"(accB1[4 * rg + 1]));
    asm("v_cvt_pk_bf16_f32 %0, %1, %2" : "=v"(pb1[1]) : "v"(accB1[4 * rg + 2]), "v"(accB1[4 * rg + 3]));
    *(uint2*)(obA + 8 * rg + 4 * hi) = *(uint2*)pa0;
    *(uint2*)(obA + 32 + 8 * rg + 4 * hi) = *(uint2*)pa1;
    *(uint2*)(obB + 8 * rg + 4 * hi) = *(uint2*)pb0;
    *(uint2*)(obB + 32 + 8 * rg + 4 * hi) = *(uint2*)pb1;
  }
}

// ---------------- combine 2 halves (bf16) + normalize + inverse RoPE -> ao ----------------
__global__ __launch_bounds__(256) void k_combine(const unsigned short* __restrict__ opart,
                                                 const float* __restrict__ lpart,
                                                 const float* __restrict__ cosT,
                                                 const float* __restrict__ sinT,
                                                 unsigned short* __restrict__ ao) {
  int bh = blockIdx.y;
  int b = bh >> 3, h = bh & 7;
  int t = threadIdx.x;
  int q = blockIdx.x * 16 + (t >> 4);
  int d = (t & 15) * 4;
  size_t i0 = (size_t)bh * NSEQ + q;
  const size_t HOFF = (size_t)16 * NSEQ;
  float l = lpart[i0] + lpart[i0 + HOFF];
  float o[4] = {0.f, 0.f, 0.f, 0.f};
#pragma unroll
  for (int p = 0; p < 2; ++p) {
    uint2 u = *(const uint2*)(opart + (i0 + p * HOFF) * 64 + d);
    o[0] += bf2f((unsigned short)(u.x & 0xffff));
    o[1] += bf2f((unsigned short)(u.x >> 16));
    o[2] += bf2f((unsigned short)(u.y & 0xffff));
    o[3] += bf2f((unsigned short)(u.y >> 16));
  }
  float inv = 1.0f / l;
  float4 c4 = *(const float4*)(cosT + ((size_t)b * NSEQ + q) * 64 + d);
  float4 s4 = *(const float4*)(sinT + ((size_t)b * NSEQ + q) * 64 + d);
  float yx = o[0] * inv;
  float yy = o[1] * inv;
  float yz = o[2] * inv;
  float yw = o[3] * inv;
  float r0 = yx * c4.x + yy * s4.x;
  float r1 = yy * c4.y - yx * s4.y;
  float r2 = yz * c4.z + yw * s4.z;
  float r3 = yw * c4.w - yz * s4.w;
  unsigned int w0, w1;
  asm("v_cvt_pk_bf16_f32 %0, %1, %2" : "=v"(w0) : "v"(r0), "v"(r1));
  asm("v_cvt_pk_bf16_f32 %0, %1, %2" : "=v"(w1) : "v"(r2), "v"(r3));
  unsigned int uu[2] = {w0, w1};
  *(uint2*)(ao + ((size_t)b * NSEQ + q) * DIM + h * 64 + d) = *(uint2*)uu;
}

extern "C" void kernel_launch(void* const* d_in, const int* in_sizes, int n_in,
                              void* d_out, int out_size, void* d_ws, size_t ws_size,
                              hipStream_t stream) {
  const float* x    = (const float*)d_in[0];
  const float* rot  = (const float*)d_in[1];
  const float* lnw  = (const float*)d_in[2];
  const float* lnb  = (const float*)d_in[3];
  const float* wqkv = (const float*)d_in[4];
  const float* wout = (const float*)d_in[5];
  const float* bout = (const float*)d_in[6];
  float* out = (float*)d_out;

  char* ws = (char*)d_ws;
  const size_t MB = (size_t)1 << 20;
  float* cosT          = (float*)(ws + 0 * MB);        // 2 MB
  float* sinT          = (float*)(ws + 2 * MB);        // 2 MB
  unsigned short* wqkb = (unsigned short*)(ws + 4 * MB);   // 1.5 MB (dead after gemm0)
  float* lpart         = (float*)(ws + 5 * MB + 512 * 1024); // 512 KB
  unsigned short* wob  = (unsigned short*)(ws + 6 * MB);   // 0.5 MB
  unsigned short* xn   = (unsigned short*)(ws + 8 * MB);   // 8 MB (dead after gemm0)
  unsigned short* opart = (unsigned short*)(ws + 8 * MB);  // 16 MB bf16 (8-24, attn -> combine)
  unsigned short* qkv  = (unsigned short*)(ws + 16 * MB);  // 24 MB (dead after rope_split)
  unsigned short* qh   = (unsigned short*)(ws + 40 * MB);  // 8 MB (dead after attn)
  unsigned short* ao   = (unsigned short*)(ws + 40 * MB);  // 8 MB (combine -> gemm1)
  unsigned short* kh   = (unsigned short*)(ws + 48 * MB);  // 8 MB
  unsigned short* vt   = (unsigned short*)(ws + 56 * MB);  // 8 MB

  k_prep<<<8192, 256, 0, stream>>>(rot, cosT, sinT, wqkv, wqkb, wout, wob,
                                   x, lnw, lnb, xn);
  k_gemm<0, 128><<<dim3(NROWS / 128, QKVN / 128), 256, 0, stream>>>(xn, wqkb, qkv, nullptr,
                                                                    NROWS, QKVN, DIM);
  k_rope_split<<<dim3(NSEQ / 128, 16), 256, 0, stream>>>(qkv, cosT, sinT, qh, kh, vt);
  k_attn<<<512, 256, 0, stream>>>(qh, kh, vt, opart, lpart);
  k_combine<<<dim3(NSEQ / 16, 16), 256, 0, stream>>>(opart, lpart, cosT, sinT, ao);
  k_gemm<1, 64><<<dim3(NROWS / 64, DIM / 128), 256, 0, stream>>>(ao, wob, out, bout,
                                                                 NROWS, DIM, DIM);
}

// Round 15
// 134.309 us; speedup vs baseline: 4.3299x; 1.0127x over previous
//
#include <hip/hip_runtime.h>
#include <cmath>

typedef short bf16x8 __attribute__((ext_vector_type(8)));
typedef float f32x2 __attribute__((ext_vector_type(2)));
typedef float f32x4 __attribute__((ext_vector_type(4)));
typedef float f32x16 __attribute__((ext_vector_type(16)));

#define NSEQ 4096
#define BATCH 2
#define DIM 512
#define HEADS 8
#define NROWS (BATCH * NSEQ)   // 8192
#define QKVN (3 * DIM)         // 1536

__device__ __forceinline__ unsigned short f2bf(float f) {
  unsigned int u = __float_as_uint(f);
  u += 0x7fffu + ((u >> 16) & 1u);
  return (unsigned short)(u >> 16);
}
__device__ __forceinline__ float bf2f(unsigned short h) {
  return __uint_as_float(((unsigned int)h) << 16);
}
__device__ __forceinline__ void gload16(const unsigned short* g, unsigned short* l) {
  __builtin_amdgcn_global_load_lds((const __attribute__((address_space(1))) unsigned int*)g,
                                   (__attribute__((address_space(3))) unsigned int*)l, 16, 0, 0);
}

// ---------------- fused prep: trig tables (HW sin/cos) + weight cvts + LayerNorm ----------------
// blocks [0,2048): tables; [2048,5120): wqkv cvt; [5120,6144): wout cvt; [6144,8192): LN
__global__ __launch_bounds__(256) void k_prep(const float* __restrict__ rot,
                                              float* __restrict__ cosT,
                                              float* __restrict__ sinT,
                                              const float* __restrict__ wqkv,
                                              unsigned short* __restrict__ wqkb,
                                              const float* __restrict__ wout,
                                              unsigned short* __restrict__ wob,
                                              const float* __restrict__ x,
                                              const float* __restrict__ lnw,
                                              const float* __restrict__ lnb,
                                              unsigned short* __restrict__ xn) {
  const float INV2PI = 0.15915494309f;
  int bid = blockIdx.x;
  int t = threadIdx.x;
  if (bid < 2048) {
    int i = bid * 256 + t;
    float rv = rot[i] * INV2PI;           // v_sin/v_cos take revolutions
    cosT[i] = __builtin_amdgcn_cosf(rv);
    sinT[i] = __builtin_amdgcn_sinf(rv);
  } else if (bid < 5120) {
    int i = (bid - 2048) * 256 + t;
    wqkb[i] = f2bf(wqkv[i]);
  } else if (bid < 6144) {
    int i = (bid - 5120) * 256 + t;
    wob[i] = f2bf(wout[i]);
  } else {
    int row = (bid - 6144) * 4 + (t >> 6);
    int lane = t & 63;
    const float* xr = x + (size_t)row * DIM;
    float v[8];
    float s = 0.f;
#pragma unroll
    for (int j = 0; j < 8; ++j) { v[j] = xr[lane + j * 64]; s += v[j]; }
#pragma unroll
    for (int m = 1; m < 64; m <<= 1) s += __shfl_xor(s, m);
    float mu = s * (1.0f / DIM);
    float q = 0.f;
#pragma unroll
    for (int j = 0; j < 8; ++j) { float d = v[j] - mu; q += d * d; }
#pragma unroll
    for (int m = 1; m < 64; m <<= 1) q += __shfl_xor(q, m);
    float rs = rsqrtf(q * (1.0f / DIM) + 1e-5f);
#pragma unroll
    for (int j = 0; j < 8; ++j) {
      int col = lane + j * 64;
      xn[(size_t)row * DIM + col] = f2bf((v[j] - mu) * rs * lnw[col] + lnb[col]);
    }
  }
}

// ---------------- GEMM: C = A[M][K] * B[N][K]^T — 3-buffer ring, counted vmcnt ----
// TM = block M-tile (128 or 64); N-tile fixed 128. 4 waves: wave tile (TM/2) x 64.
// Per step: stage(t+1)->buf[(t+1)%3]; s_waitcnt vmcnt(S) (own stage(t) done, stage(t+1)
// in flight ACROSS the barrier); s_barrier; compute buf[t%3]. Never drains to 0 until tail.
// Race audit: 1 barrier/iter bounds skew <1 iter; writer buf[(t+2)%3] vs slow reader
// buf[t%3] distinct; buf[(t+2)%3]'s prior readers (compute(t-1)) finished pre-barrier(t).
template <int EPI, int TM>
__global__ __launch_bounds__(256) void k_gemm(const unsigned short* __restrict__ A,
                                              const unsigned short* __restrict__ B,
                                              void* __restrict__ C,
                                              const float* __restrict__ bias,
                                              int M, int N, int K) {
  constexpr int MI = TM / 32;  // acc rows per wave (4 or 2)
  __shared__ __align__(16) unsigned short As[3][TM * 32];
  __shared__ __align__(16) unsigned short Bs[3][128 * 32];
  int bm = blockIdx.x, bn = blockIdx.y;
  int tid = threadIdx.x;
  int lane = tid & 63, w = tid >> 6;
  int wm = (w >> 1) * (TM / 2), wn = (w & 1) << 6;
  f32x4 acc[MI][4] = {};

#define GSTAGE(KT, BUF) do { \
  if constexpr (TM == 128) { \
    _Pragma("unroll") \
    for (int i = 0; i < 2; ++i) { \
      int c = tid + (i << 8); \
      int row = c >> 2, kc = (c & 3) << 3; \
      gload16(A + (size_t)(bm * 128 + row) * K + (KT) + kc, &As[BUF][(w * 64 + i * 256) * 8]); \
    } \
  } else { \
    int row = tid >> 2, kc = (tid & 3) << 3; \
    gload16(A + (size_t)(bm * 64 + row) * K + (KT) + kc, &As[BUF][(w * 64) * 8]); \
  } \
  _Pragma("unroll") \
  for (int i = 0; i < 2; ++i) { \
    int c = tid + (i << 8); \
    int row = c >> 2, kc = (c & 3) << 3; \
    gload16(B + (size_t)(bn * 128 + row) * K + (KT) + kc, &Bs[BUF][(w * 64 + i * 256) * 8]); \
  } } while (0)

  GSTAGE(0, 0);
  int nk = K >> 5;
  int rbuf = 0, wbuf = 1;
  for (int t = 0; t < nk; ++t) {
    if (t + 1 < nk) {
      GSTAGE((t + 1) << 5, wbuf);
      if constexpr (TM == 128) {
        asm volatile("s_waitcnt vmcnt(4)" ::: "memory");
      } else {
        asm volatile("s_waitcnt vmcnt(3)" ::: "memory");
      }
    } else {
      asm volatile("s_waitcnt vmcnt(0)" ::: "memory");
    }
    __builtin_amdgcn_s_barrier();
    asm volatile("" ::: "memory");
    bf16x8 af[MI], bfr[4];
#pragma unroll
    for (int mi = 0; mi < MI; ++mi)
      af[mi] = *(const bf16x8*)&As[rbuf][(wm + mi * 16 + (lane & 15)) * 32 + ((lane >> 4) << 3)];
#pragma unroll
    for (int ni = 0; ni < 4; ++ni)
      bfr[ni] = *(const bf16x8*)&Bs[rbuf][(wn + ni * 16 + (lane & 15)) * 32 + ((lane >> 4) << 3)];
#pragma unroll
    for (int mi = 0; mi < MI; ++mi)
#pragma unroll
      for (int ni = 0; ni < 4; ++ni)
        acc[mi][ni] = __builtin_amdgcn_mfma_f32_16x16x32_bf16(af[mi], bfr[ni], acc[mi][ni], 0, 0, 0);
    rbuf = (rbuf == 2) ? 0 : rbuf + 1;
    wbuf = (wbuf == 2) ? 0 : wbuf + 1;
  }
#undef GSTAGE
#pragma unroll
  for (int mi = 0; mi < MI; ++mi) {
#pragma unroll
    for (int ni = 0; ni < 4; ++ni) {
#pragma unroll
      for (int r = 0; r < 4; ++r) {
        int gm = bm * TM + wm + mi * 16 + ((lane >> 4) << 2) + r;
        int gn = bn * 128 + wn + ni * 16 + (lane & 15);
        if (EPI == 0) {
          ((unsigned short*)C)[(size_t)gm * N + gn] = f2bf(acc[mi][ni][r]);
        } else {
          ((float*)C)[(size_t)gm * N + gn] = acc[mi][ni][r] + bias[gn];
        }
      }
    }
  }
}

// ------ RoPE + head split (+ V transpose); Q pre-scaled by 0.125*log2(e) (exp2-domain) ------
__global__ __launch_bounds__(256) void k_rope_split(const unsigned short* __restrict__ qkv,
                                                    const float* __restrict__ cosT,
                                                    const float* __restrict__ sinT,
                                                    unsigned short* __restrict__ qh,
                                                    unsigned short* __restrict__ kh,
                                                    unsigned short* __restrict__ vt) {
  __shared__ unsigned short vs[128][65];
  const float QSC = 0.125f * 1.44269504f;
  int nt = blockIdx.x, bh = blockIdx.y;
  int b = bh >> 3, h = bh & 7;
  int n0 = nt * 128;
  int t = threadIdx.x;
  int sub = t >> 3, cc = t & 7;
#pragma unroll
  for (int rr = 0; rr < 4; ++rr) {
    int row = rr * 32 + sub;
    int n = n0 + row;
    size_t base = ((size_t)(b * NSEQ + n)) * QKVN + h * 64 + cc * 8;
    const float* cb = cosT + ((size_t)(b * NSEQ + n)) * 64 + cc * 8;
    const float* sb = sinT + ((size_t)(b * NSEQ + n)) * 64 + cc * 8;
    float c[8], sn[8];
#pragma unroll
    for (int j = 0; j < 8; ++j) { c[j] = cb[j]; sn[j] = sb[j]; }
    bf16x8 qv = *(const bf16x8*)(qkv + base);
    bf16x8 kv = *(const bf16x8*)(qkv + base + 512);
    bf16x8 vv = *(const bf16x8*)(qkv + base + 1024);
    union { bf16x8 v; unsigned short u[8]; } yq, yk;
#pragma unroll
    for (int j = 0; j < 8; j += 2) {
      {
        float e = bf2f((unsigned short)qv[j]), o = bf2f((unsigned short)qv[j + 1]);
        yq.u[j]     = f2bf((e * c[j] - o * sn[j]) * QSC);
        yq.u[j + 1] = f2bf((o * c[j + 1] + e * sn[j + 1]) * QSC);
      }
      {
        float e = bf2f((unsigned short)kv[j]), o = bf2f((unsigned short)kv[j + 1]);
        yk.u[j]     = f2bf(e * c[j] - o * sn[j]);
        yk.u[j + 1] = f2bf(o * c[j + 1] + e * sn[j + 1]);
      }
      {
        float e = bf2f((unsigned short)vv[j]), o = bf2f((unsigned short)vv[j + 1]);
        vs[row][cc * 8 + j]     = f2bf(e * c[j] - o * sn[j]);
        vs[row][cc * 8 + j + 1] = f2bf(o * c[j + 1] + e * sn[j + 1]);
      }
    }
    *(bf16x8*)(qh + ((size_t)bh * NSEQ + n) * 64 + cc * 8) = yq.v;
    *(bf16x8*)(kh + ((size_t)bh * NSEQ + n) * 64 + cc * 8) = yk.v;
  }
  __syncthreads();
  int d = t >> 2, c4 = t & 3;
#pragma unroll
  for (int g = 0; g < 4; ++g) {
    union { bf16x8 v; unsigned short u[8]; } tv;
#pragma unroll
    for (int j = 0; j < 8; ++j) tv.u[j] = vs[c4 * 32 + g * 8 + j][d];
    *(bf16x8*)(vt + ((size_t)bh * 64 + d) * NSEQ + n0 + c4 * 32 + g * 8) = tv.v;
  }
}

// ---------------- Flash attention (= round-14, unchanged): KV-split-2, 64q/wave ----
// 512 blocks x 4 waves; 4-buffer LDS ring, depth-2 prefetch, counted vmcnt(8) + raw
// s_barrier per tile (never drain in steady state). shfl_xor exchange (proven).
__global__ __launch_bounds__(256, 2) void k_attn(const unsigned short* __restrict__ Qh,
                                                 const unsigned short* __restrict__ Kh,
                                                 const unsigned short* __restrict__ VT,
                                                 unsigned short* __restrict__ opart,
                                                 float* __restrict__ lpart) {
  __shared__ __align__(16) unsigned short Ks[4][64 * 64];
  __shared__ __align__(16) unsigned short Vs[4][64 * 64];
  int bid = blockIdx.x;
  int bh   = (bid & 7) + 8 * ((bid >> 7) & 1);  // XCD-pinned: bh%8 == bid%8
  int qt   = (bid >> 3) & 15;
  int half = (bid >> 8) & 1;
  int tid = threadIdx.x;
  int w = tid >> 6, lane = tid & 63;
  int lq = lane & 31, hi = lane >> 5;
  int q0 = qt * 256 + w * 64;
  int kv0 = half * 2048;

  const unsigned short* Kbh = Kh + (size_t)bh * NSEQ * 64;
  const unsigned short* Vbh = VT + (size_t)bh * 64 * NSEQ;

  const unsigned short* QbA = Qh + ((size_t)bh * NSEQ + q0 + lq) * 64 + hi * 8;
  const unsigned short* QbB = QbA + 32 * 64;
  bf16x8 qfA[4], qfB[4];
#pragma unroll
  for (int j = 0; j < 4; ++j) {
    qfA[j] = *(const bf16x8*)(QbA + j * 16);
    qfB[j] = *(const bf16x8*)(QbB + j * 16);
  }

  // staging chunk geometry: chunk c -> row r=c>>3, source 16B slot (c&7)^(r&7)
  int c0 = w * 64 + lane;
  int r0 = c0 >> 3, sw0 = ((c0 & 7) ^ (r0 & 7)) << 3;
  int c1 = c0 + 256;
  int r1 = c1 >> 3, sw1 = ((c1 & 7) ^ (r1 & 7)) << 3;
  int ld0 = (w * 64) * 8, ld1 = (256 + w * 64) * 8;

  f32x16 accA0 = (f32x16)0.0f, accA1 = (f32x16)0.0f;
  f32x16 accB0 = (f32x16)0.0f, accB1 = (f32x16)0.0f;
  float lA = 0.f, lB = 0.f;
  int swz = (lq & 7) << 4;

#define STAGE(T, BUF) do { \
  int tg_ = kv0 + (T) * 64; \
  gload16(Kbh + ((size_t)tg_ + r0) * 64 + sw0, &Ks[BUF][ld0]); \
  gload16(Kbh + ((size_t)tg_ + r1) * 64 + sw1, &Ks[BUF][ld1]); \
  gload16(Vbh + (size_t)r0 * NSEQ + tg_ + sw0, &Vs[BUF][ld0]); \
  gload16(Vbh + (size_t)r1 * NSEQ + tg_ + sw1, &Vs[BUF][ld1]); \
} while (0)

  // prologue: prefetch tiles 0 and 1 (8 loads in flight)
  STAGE(0, 0);
  STAGE(1, 1);

  for (int t = 0; t < 32; ++t) {
    int rd = t & 3;
    if (t < 30) {
      STAGE(t + 2, (t + 2) & 3);
      asm volatile("s_waitcnt vmcnt(8)" ::: "memory");
    } else if (t == 30) {
      asm volatile("s_waitcnt vmcnt(4)" ::: "memory");
    } else {
      asm volatile("s_waitcnt vmcnt(0)" ::: "memory");
    }
    __builtin_amdgcn_s_barrier();
    asm volatile("" ::: "memory");
    const char* kb_ = (const char*)&Ks[rd][0];
    const char* vb_ = (const char*)&Vs[rd][0];
#pragma unroll
    for (int ph = 0; ph < 2; ++ph) {
      // ---- QK^T: 32 k-rows x 64 q (each a-read feeds both q-frags) ----
      f32x16 sA = (f32x16)0.0f, sB = (f32x16)0.0f;
      __builtin_amdgcn_s_setprio(1);
#pragma unroll
      for (int j = 0; j < 4; ++j) {
        int cb = j * 32 + hi * 16;
        bf16x8 a = *(const bf16x8*)(kb_ + (ph * 32 + lq) * 128 + (cb ^ swz));
        sA = __builtin_amdgcn_mfma_f32_32x32x16_bf16(a, qfA[j], sA, 0, 0, 0);
        sB = __builtin_amdgcn_mfma_f32_32x32x16_bf16(a, qfB[j], sB, 0, 0, 0);
      }
      __builtin_amdgcn_s_setprio(0);
      // ---- exp2 (raw) + packed sums ----
#pragma unroll
      for (int r = 0; r < 16; ++r) sA[r] = __builtin_amdgcn_exp2f(sA[r]);
#pragma unroll
      for (int r = 0; r < 16; ++r) sB[r] = __builtin_amdgcn_exp2f(sB[r]);
      {
        union { f32x16 v; f32x2 p[8]; } ua, ub; ua.v = sA; ub.v = sB;
        f32x2 a01 = ua.p[0] + ua.p[1], a23 = ua.p[2] + ua.p[3];
        f32x2 a45 = ua.p[4] + ua.p[5], a67 = ua.p[6] + ua.p[7];
        f32x2 ta = (a01 + a23) + (a45 + a67);
        lA += ta.x + ta.y;
        f32x2 b01 = ub.p[0] + ub.p[1], b23 = ub.p[2] + ub.p[3];
        f32x2 b45 = ub.p[4] + ub.p[5], b67 = ub.p[6] + ub.p[7];
        f32x2 tb = (b01 + b23) + (b45 + b67);
        lB += tb.x + tb.y;
      }
      // ---- pack P -> bf16 ----
      unsigned int dwA[8], dwB[8];
#pragma unroll
      for (int m = 0; m < 8; ++m) {
        asm("v_cvt_pk_bf16_f32 %0, %1, %2" : "=v"(dwA[m]) : "v"(sA[2 * m]), "v"(sA[2 * m + 1]));
        asm("v_cvt_pk_bf16_f32 %0, %1, %2" : "=v"(dwB[m]) : "v"(sB[2 * m]), "v"(sB[2 * m + 1]));
      }
      // ---- PV: each v-read feeds both q-frags; exchange via shfl_xor (proven) ----
      __builtin_amdgcn_s_setprio(1);
#pragma unroll
      for (int kk = 0; kk < 2; ++kk) {
        const int B = 4 * kk;
        unsigned int svA0 = hi ? dwA[B + 0] : dwA[B + 2];
        unsigned int svA1 = hi ? dwA[B + 1] : dwA[B + 3];
        unsigned int svB0 = hi ? dwB[B + 0] : dwB[B + 2];
        unsigned int svB1 = hi ? dwB[B + 1] : dwB[B + 3];
        unsigned int rvA0 = (unsigned int)__shfl_xor((int)svA0, 32);
        unsigned int rvA1 = (unsigned int)__shfl_xor((int)svA1, 32);
        unsigned int rvB0 = (unsigned int)__shfl_xor((int)svB0, 32);
        unsigned int rvB1 = (unsigned int)__shfl_xor((int)svB1, 32);
        union { unsigned int d[4]; bf16x8 v; } puA, puB;
        puA.d[0] = hi ? rvA0 : dwA[B + 0];
        puA.d[1] = hi ? rvA1 : dwA[B + 1];
        puA.d[2] = hi ? dwA[B + 2] : rvA0;
        puA.d[3] = hi ? dwA[B + 3] : rvA1;
        puB.d[0] = hi ? rvB0 : dwB[B + 0];
        puB.d[1] = hi ? rvB1 : dwB[B + 1];
        puB.d[2] = hi ? dwB[B + 2] : rvB0;
        puB.d[3] = hi ? dwB[B + 3] : rvB1;
        int cb = (ph * 2 + kk) * 32 + hi * 16;
        bf16x8 v0 = *(const bf16x8*)(vb_ + lq * 128 + (cb ^ swz));
        bf16x8 v1 = *(const bf16x8*)(vb_ + (32 + lq) * 128 + (cb ^ swz));
        accA0 = __builtin_amdgcn_mfma_f32_32x32x16_bf16(v0, puA.v, accA0, 0, 0, 0);
        accA1 = __builtin_amdgcn_mfma_f32_32x32x16_bf16(v1, puA.v, accA1, 0, 0, 0);
        accB0 = __builtin_amdgcn_mfma_f32_32x32x16_bf16(v0, puB.v, accB0, 0, 0, 0);
        accB1 = __builtin_amdgcn_mfma_f32_32x32x16_bf16(v1, puB.v, accB1, 0, 0, 0);
      }
      __builtin_amdgcn_s_setprio(0);
    }
  }
#undef STAGE

  // ---- epilogue: write bf16 partials for both q-frags ----
  float lsumA = lA + __shfl_xor(lA, 32);
  float lsumB = lB + __shfl_xor(lB, 32);
  size_t qrowA = (size_t)(half * 16 + bh) * NSEQ + q0 + lq;
  size_t qrowB = qrowA + 32;
  if (hi == 0) {
    lpart[qrowA] = lsumA;
    lpart[qrowB] = lsumB;
  }
  unsigned short* obA = opart + qrowA * 64;
  unsigned short* obB = opart + qrowB * 64;
#pragma unroll
  for (int rg = 0; rg < 4; ++rg) {
    unsigned int pa0[2], pa1[2], pb0[2], pb1[2];
    asm("v_cvt_pk_bf16_f32 %0, %1, %2" : "=v"(pa0[0]) : "v"(accA0[4 * rg + 0]), "v"(accA0[4 * rg + 1]));
    asm("v_cvt_pk_bf16_f32 %0, %1, %2" : "=v"(pa0[1]) : "v"(accA0[4 * rg + 2]), "v"(accA0[4 * rg + 3]));
    asm("v_cvt_pk_bf16_f32 %0, %1, %2" : "=v"(pa1[0]) : "v"(accA1[4 * rg + 0]), "v"(accA1[4 * rg + 1]));
    asm("v_cvt_pk_bf16_f32 %0, %1, %2" : "=v"(pa1[1]) : "v"(accA1[4 * rg + 2]), "v"(accA1[4 * rg + 3]));
    asm("v_cvt_pk_bf16_f32 %0, %1, %2" : "=v"(pb0[0]) : "v"(accB0[4 * rg + 0]), "v"(accB0[4 * rg + 1]));
    asm("v_cvt_pk_bf16_f32 %0, %1, %2" : "=v"(pb0[1]) : "v"(accB0[4 * rg + 2]), "v"(accB0[4 * rg + 3]));
    asm("v_cvt_pk_bf16_f32 %0, %1, %2" : "=v"(pb1[0]) : "v"(accB1[4 * rg + 0]), "v"(accB1[4 * rg + 1]));
    asm("v_cvt_pk_bf16_f32 %0, %1, %2" : "=v"(pb1[1]) : "v"(accB1[4 * rg + 2]), "v"(accB1[4 * rg + 3]));
    *(uint2*)(obA + 8 * rg + 4 * hi) = *(uint2*)pa0;
    *(uint2*)(obA + 32 + 8 * rg + 4 * hi) = *(uint2*)pa1;
    *(uint2*)(obB + 8 * rg + 4 * hi) = *(uint2*)pb0;
    *(uint2*)(obB + 32 + 8 * rg + 4 * hi) = *(uint2*)pb1;
  }
}

// ---------------- combine 2 halves (bf16) + normalize + inverse RoPE -> ao ----------------
__global__ __launch_bounds__(256) void k_combine(const unsigned short* __restrict__ opart,
                                                 const float* __restrict__ lpart,
                                                 const float* __restrict__ cosT,
                                                 const float* __restrict__ sinT,
                                                 unsigned short* __restrict__ ao) {
  int bh = blockIdx.y;
  int b = bh >> 3, h = bh & 7;
  int t = threadIdx.x;
  int q = blockIdx.x * 16 + (t >> 4);
  int d = (t & 15) * 4;
  size_t i0 = (size_t)bh * NSEQ + q;
  const size_t HOFF = (size_t)16 * NSEQ;
  float l = lpart[i0] + lpart[i0 + HOFF];
  float o[4] = {0.f, 0.f, 0.f, 0.f};
#pragma unroll
  for (int p = 0; p < 2; ++p) {
    uint2 u = *(const uint2*)(opart + (i0 + p * HOFF) * 64 + d);
    o[0] += bf2f((unsigned short)(u.x & 0xffff));
    o[1] += bf2f((unsigned short)(u.x >> 16));
    o[2] += bf2f((unsigned short)(u.y & 0xffff));
    o[3] += bf2f((unsigned short)(u.y >> 16));
  }
  float inv = 1.0f / l;
  float4 c4 = *(const float4*)(cosT + ((size_t)b * NSEQ + q) * 64 + d);
  float4 s4 = *(const float4*)(sinT + ((size_t)b * NSEQ + q) * 64 + d);
  float yx = o[0] * inv;
  float yy = o[1] * inv;
  float yz = o[2] * inv;
  float yw = o[3] * inv;
  float r0 = yx * c4.x + yy * s4.x;
  float r1 = yy * c4.y - yx * s4.y;
  float r2 = yz * c4.z + yw * s4.z;
  float r3 = yw * c4.w - yz * s4.w;
  unsigned int w0, w1;
  asm("v_cvt_pk_bf16_f32 %0, %1, %2" : "=v"(w0) : "v"(r0), "v"(r1));
  asm("v_cvt_pk_bf16_f32 %0, %1, %2" : "=v"(w1) : "v"(r2), "v"(r3));
  unsigned int uu[2] = {w0, w1};
  *(uint2*)(ao + ((size_t)b * NSEQ + q) * DIM + h * 64 + d) = *(uint2*)uu;
}

extern "C" void kernel_launch(void* const* d_in, const int* in_sizes, int n_in,
                              void* d_out, int out_size, void* d_ws, size_t ws_size,
                              hipStream_t stream) {
  const float* x    = (const float*)d_in[0];
  const float* rot  = (const float*)d_in[1];
  const float* lnw  = (const float*)d_in[2];
  const float* lnb  = (const float*)d_in[3];
  const float* wqkv = (const float*)d_in[4];
  const float* wout = (const float*)d_in[5];
  const float* bout = (const float*)d_in[6];
  float* out = (float*)d_out;

  char* ws = (char*)d_ws;
  const size_t MB = (size_t)1 << 20;
  float* cosT          = (float*)(ws + 0 * MB);        // 2 MB
  float* sinT          = (float*)(ws + 2 * MB);        // 2 MB
  unsigned short* wqkb = (unsigned short*)(ws + 4 * MB);   // 1.5 MB (dead after gemm0)
  float* lpart         = (float*)(ws + 5 * MB + 512 * 1024); // 512 KB
  unsigned short* wob  = (unsigned short*)(ws + 6 * MB);   // 0.5 MB
  unsigned short* xn   = (unsigned short*)(ws + 8 * MB);   // 8 MB (dead after gemm0)
  unsigned short* opart = (unsigned short*)(ws + 8 * MB);  // 16 MB bf16 (8-24, attn -> combine)
  unsigned short* qkv  = (unsigned short*)(ws + 16 * MB);  // 24 MB (dead after rope_split)
  unsigned short* qh   = (unsigned short*)(ws + 40 * MB);  // 8 MB (dead after attn)
  unsigned short* ao   = (unsigned short*)(ws + 40 * MB);  // 8 MB (combine -> gemm1)
  unsigned short* kh   = (unsigned short*)(ws + 48 * MB);  // 8 MB
  unsigned short* vt   = (unsigned short*)(ws + 56 * MB);  // 8 MB

  k_prep<<<8192, 256, 0, stream>>>(rot, cosT, sinT, wqkv, wqkb, wout, wob,
                                   x, lnw, lnb, xn);
  k_gemm<0, 128><<<dim3(NROWS / 128, QKVN / 128), 256, 0, stream>>>(xn, wqkb, qkv, nullptr,
                                                                    NROWS, QKVN, DIM);
  k_rope_split<<<dim3(NSEQ / 128, 16), 256, 0, stream>>>(qkv, cosT, sinT, qh, kh, vt);
  k_attn<<<512, 256, 0, stream>>>(qh, kh, vt, opart, lpart);
  k_combine<<<dim3(NSEQ / 16, 16), 256, 0, stream>>>(opart, lpart, cosT, sinT, ao);
  k_gemm<1, 64><<<dim3(NROWS / 64, DIM / 128), 256, 0, stream>>>(ao, wob, out, bout,
                                                                 NROWS, DIM, DIM);
}